// Round 10
// baseline (134.059 us; speedup 1.0000x reference)
//
#include <hip/hip_runtime.h>
#include <math.h>

#define DIMC 512
#define HW 4096
#define SCALE 0.125f
#define EPSN 1e-12f

typedef __attribute__((ext_vector_type(8))) short bf16x8;
typedef __attribute__((ext_vector_type(4))) float f32x4;

__device__ __forceinline__ unsigned short f2bf(float f) {
    union { float f; unsigned int u; } v; v.f = f;
    unsigned int u = v.u;
    return (unsigned short)((u + 0x7fffu + ((u >> 16) & 1u)) >> 16);
}
__device__ __forceinline__ float bf2f(unsigned short h) {
    union { unsigned int u; float f; } v; v.u = ((unsigned int)h) << 16;
    return v.f;
}

union Pack8 { int4 v; unsigned short u[8]; };

// async global->LDS, 16B per lane, wave-uniform LDS base (HW: base + lane*16)
__device__ __forceinline__ void gload_lds16(const unsigned short* src, char* ldst) {
    __builtin_amdgcn_global_load_lds(
        (const __attribute__((address_space(1))) void*)src,
        (__attribute__((address_space(3))) void*)ldst, 16, 0, 0);
}

// ---------------------------------------------------------------------------
// P1: convert Wq,Wk fp32 -> Wb bf16 [2][512][512] (stacked)
// ---------------------------------------------------------------------------
__global__ __launch_bounds__(256) void convert_w(
    const float* __restrict__ Wq, const float* __restrict__ Wk,
    unsigned short* __restrict__ Wb)
{
    int i = (blockIdx.x * 256 + threadIdx.x) * 4;   // [0, 524288)
    const float* s = (i < 262144) ? Wq : Wk;
    int off = i & 262143;
    float4 v4 = *(const float4*)(s + off);
    ushort4 o;
    o.x = f2bf(v4.x); o.y = f2bf(v4.y); o.z = f2bf(v4.z); o.w = f2bf(v4.w);
    *(ushort4*)(Wb + i) = o;
}

// ---------------------------------------------------------------------------
// P1b: WvT[c3][c'] = bf16(Wv[c'][c3])  (512x512 transpose+convert)
// ---------------------------------------------------------------------------
__global__ __launch_bounds__(256) void wvt_conv(
    const float* __restrict__ Wv, unsigned short* __restrict__ WvT)
{
    const int cp0 = blockIdx.y * 64;   // c' tile
    const int c30 = blockIdx.x * 64;   // c3 tile
    __shared__ unsigned short sT[64][65];
    const int t = threadIdx.x;
    #pragma unroll
    for (int i = 0; i < 4; ++i) {
        int ch = t + i * 256;
        int r = ch >> 4, col4 = (ch & 15) * 4;
        float4 v4 = *(const float4*)(Wv + (size_t)(cp0 + r) * DIMC + c30 + col4);
        sT[r][col4 + 0] = f2bf(v4.x); sT[r][col4 + 1] = f2bf(v4.y);
        sT[r][col4 + 2] = f2bf(v4.z); sT[r][col4 + 3] = f2bf(v4.w);
    }
    __syncthreads();
    #pragma unroll
    for (int i = 0; i < 2; ++i) {
        int ch = t + i * 256;
        int n = ch >> 3, cc = (ch & 7) * 8;   // n = c3-local
        Pack8 pk;
        #pragma unroll
        for (int e = 0; e < 8; ++e) pk.u[e] = sT[cc + e][n];
        *(int4*)(WvT + (size_t)(c30 + n) * DIMC + cp0 + cc) = pk.v;
    }
}

// ---------------------------------------------------------------------------
// P2: prep_x: x[b][c][n] fp32 -> xT[b][n][c] bf16 (unmasked, for final GEMM B)
//                            -> xmb[b][c][n] bf16 masked (for Gram)
// ---------------------------------------------------------------------------
__global__ __launch_bounds__(256) void prep_x(
    const float* __restrict__ x, const float* __restrict__ mask,
    unsigned short* __restrict__ xT, unsigned short* __restrict__ xmb)
{
    const int b  = blockIdx.z;
    const int c0 = blockIdx.y * 64;
    const int n0 = blockIdx.x * 64;
    __shared__ unsigned short sT[64][65];
    const int t = threadIdx.x;
    #pragma unroll
    for (int i = 0; i < 4; ++i) {
        int ch = t + i * 256;
        int r = ch >> 4, col4 = (ch & 15) * 4;
        float4 v4 = *(const float4*)(x + ((size_t)b * DIMC + c0 + r) * HW + n0 + col4);
        sT[r][col4 + 0] = f2bf(v4.x); sT[r][col4 + 1] = f2bf(v4.y);
        sT[r][col4 + 2] = f2bf(v4.z); sT[r][col4 + 3] = f2bf(v4.w);
        float4 mv = *(const float4*)(mask + (size_t)b * HW + n0 + col4);
        ushort4 xm;
        xm.x = f2bf(v4.x * mv.x); xm.y = f2bf(v4.y * mv.y);
        xm.z = f2bf(v4.z * mv.z); xm.w = f2bf(v4.w * mv.w);
        *(ushort4*)(xmb + ((size_t)b * DIMC + c0 + r) * HW + n0 + col4) = xm;
    }
    __syncthreads();
    #pragma unroll
    for (int i = 0; i < 2; ++i) {
        int ch = t + i * 256;
        int n = ch >> 3, cc = (ch & 7) * 8;
        Pack8 pk;
        #pragma unroll
        for (int e = 0; e < 8; ++e) pk.u[e] = sT[cc + e][n];
        *(int4*)(xT + ((size_t)b * HW + n0 + n) * DIMC + c0 + cc) = pk.v;
    }
}

// ---------------------------------------------------------------------------
// K1: Gram GEMM, split-K (R10): Gpart[sp][b][cA][cB] fp32 =
//       sum_{n in sp*1024..+1024} xmb[cA][n] * xmb[cB][n]
// 128x128 tile, BK=64, dbuf gload_lds, grid (4,4,32) = 512 blocks (2/CU) --
// fixes R9's 1-block/CU barrier-latency bound. fp32 direct stores.
// ---------------------------------------------------------------------------
__global__ __launch_bounds__(256) void gram_mfma(
    const unsigned short* __restrict__ xmb, float* __restrict__ Gpart)
{
    const int b   = blockIdx.z & 7;
    const int sp  = blockIdx.z >> 3;
    const int cA0 = blockIdx.y * 128;
    const int cB0 = blockIdx.x * 128;
    const unsigned short* A = xmb + (size_t)b * DIMC * HW + (size_t)cA0 * HW + sp * 1024;
    const unsigned short* B = xmb + (size_t)b * DIMC * HW + (size_t)cB0 * HW + sp * 1024;

    __shared__ __align__(16) char sm[65536];   // 2 x (A 16KB + B 16KB)

    const int t = threadIdx.x, lane = t & 63, w = t >> 6;
    const int wm = w >> 1, wn = w & 1;
    const int rsub = lane >> 3;
    const int srccol = ((lane & 7) ^ rsub) << 3;

    f32x4 zero = {0.f, 0.f, 0.f, 0.f};
    f32x4 acc[4][4];
    #pragma unroll
    for (int m = 0; m < 4; ++m)
        #pragma unroll
        for (int n = 0; n < 4; ++n) acc[m][n] = zero;

    #define STAGE_G(buf, c0)                                                  \
        {                                                                     \
            char* dst = sm + (buf) * 32768;                                   \
            _Pragma("unroll")                                                 \
            for (int i = 0; i < 4; ++i) {                                     \
                int ii = w * 4 + i;                                           \
                gload_lds16(A + (size_t)(ii * 8 + rsub) * HW + (c0) + srccol, \
                            dst + ii * 1024);                                 \
                gload_lds16(B + (size_t)(ii * 8 + rsub) * HW + (c0) + srccol, \
                            dst + 16384 + ii * 1024);                         \
            }                                                                 \
        }

    STAGE_G(0, 0);
    int cur = 0;
    for (int c0 = 0; c0 < 1024; c0 += 64) {
        __syncthreads();
        if (c0 + 64 < 1024) STAGE_G(cur ^ 1, c0 + 64);
        const char* sA = sm + cur * 32768;
        const char* sB = sA + 16384;
        #pragma unroll
        for (int s = 0; s < 2; ++s) {
            bf16x8 af[4], bfr[4];
            #pragma unroll
            for (int m = 0; m < 4; ++m) {
                int r = wm * 64 + m * 16 + (lane & 15);
                int byte = r * 128 + s * 64 + ((lane >> 4) << 4);
                byte ^= (r & 7) << 4;
                af[m] = *(const bf16x8*)(sA + byte);
            }
            #pragma unroll
            for (int n = 0; n < 4; ++n) {
                int r = wn * 64 + n * 16 + (lane & 15);
                int byte = r * 128 + s * 64 + ((lane >> 4) << 4);
                byte ^= (r & 7) << 4;
                bfr[n] = *(const bf16x8*)(sB + byte);
            }
            #pragma unroll
            for (int m = 0; m < 4; ++m)
                #pragma unroll
                for (int n = 0; n < 4; ++n)
                    acc[m][n] = __builtin_amdgcn_mfma_f32_16x16x32_bf16(
                        af[m], bfr[n], acc[m][n], 0, 0, 0);
        }
        cur ^= 1;
    }
    #undef STAGE_G

    // fp32 direct stores (16 consecutive lanes x 4B = 64B line-granular)
    float* O = Gpart + ((size_t)sp * 8 + b) * DIMC * DIMC;
    #pragma unroll
    for (int m = 0; m < 4; ++m)
        #pragma unroll
        for (int r4 = 0; r4 < 4; ++r4) {
            int row = cA0 + wm * 64 + m * 16 + ((lane >> 4) << 2) + r4;
            size_t rowbase = (size_t)row * DIMC + cB0 + wn * 64 + (lane & 15);
            #pragma unroll
            for (int n = 0; n < 4; ++n)
                O[rowbase + n * 16] = acc[m][n][r4];
        }
}

// ---------------------------------------------------------------------------
// K1b: reduce 4 fp32 split partials -> G bf16
// ---------------------------------------------------------------------------
__global__ __launch_bounds__(256) void gram_reduce(
    const float* __restrict__ Gpart, unsigned short* __restrict__ G)
{
    size_t i = ((size_t)blockIdx.x * 256 + threadIdx.x) * 4;   // over 2,097,152
    float4 a0 = *(const float4*)(Gpart + i);
    float4 a1 = *(const float4*)(Gpart + 2097152 + i);
    float4 a2 = *(const float4*)(Gpart + 4194304 + i);
    float4 a3 = *(const float4*)(Gpart + 6291456 + i);
    ushort4 o;
    o.x = f2bf(a0.x + a1.x + a2.x + a3.x);
    o.y = f2bf(a0.y + a1.y + a2.y + a3.y);
    o.z = f2bf(a0.z + a1.z + a2.z + a3.z);
    o.w = f2bf(a0.w + a1.w + a2.w + a3.w);
    *(ushort4*)(G + i) = o;
}

// ---------------------------------------------------------------------------
// K2: generic 128x128 NT GEMM, K=512, all row strides 512, bf16 out.
// C[b][j][n] = sum_k A[b][j][k] * B[b][n][k]   (batch strides as args)
// Used for: TU = [Wq|Wk] * G  (B = G rows, valid by G symmetry)
//           Wf = Wp2b * Wv    (B = WvT rows)
// ---------------------------------------------------------------------------
__global__ __launch_bounds__(256) void gemm_nn_128(
    const unsigned short* __restrict__ Ag, size_t aBatch,
    const unsigned short* __restrict__ Bg, size_t bBatch,
    unsigned short* __restrict__ Cg, size_t cBatch)
{
    const int b  = blockIdx.z;
    const int j0 = blockIdx.y * 128;
    const int n0 = blockIdx.x * 128;
    const unsigned short* A = Ag + (size_t)b * aBatch + (size_t)j0 * DIMC;
    const unsigned short* B = Bg + (size_t)b * bBatch + (size_t)n0 * DIMC;

    __shared__ __align__(16) char sm[65536];

    const int t = threadIdx.x, lane = t & 63, w = t >> 6;
    const int wm = w >> 1, wn = w & 1;
    const int rsub = lane >> 3;
    const int srccol = ((lane & 7) ^ rsub) << 3;

    f32x4 zero = {0.f, 0.f, 0.f, 0.f};
    f32x4 acc[4][4];
    #pragma unroll
    for (int m = 0; m < 4; ++m)
        #pragma unroll
        for (int n = 0; n < 4; ++n) acc[m][n] = zero;

    #define STAGE_NN(buf, c0)                                                   \
        {                                                                       \
            char* dst = sm + (buf) * 32768;                                     \
            _Pragma("unroll")                                                   \
            for (int i = 0; i < 4; ++i) {                                       \
                int ii = w * 4 + i;                                             \
                gload_lds16(A + (size_t)(ii * 8 + rsub) * DIMC + (c0) + srccol, \
                            dst + ii * 1024);                                   \
                gload_lds16(B + (size_t)(ii * 8 + rsub) * DIMC + (c0) + srccol, \
                            dst + 16384 + ii * 1024);                           \
            }                                                                   \
        }

    STAGE_NN(0, 0);
    int cur = 0;
    for (int c0 = 0; c0 < DIMC; c0 += 64) {
        __syncthreads();
        if (c0 + 64 < DIMC) STAGE_NN(cur ^ 1, c0 + 64);
        const char* sA = sm + cur * 32768;
        const char* sB = sA + 16384;
        #pragma unroll
        for (int s = 0; s < 2; ++s) {
            bf16x8 af[4], bfr[4];
            #pragma unroll
            for (int m = 0; m < 4; ++m) {
                int r = wm * 64 + m * 16 + (lane & 15);
                int byte = r * 128 + s * 64 + ((lane >> 4) << 4);
                byte ^= (r & 7) << 4;
                af[m] = *(const bf16x8*)(sA + byte);
            }
            #pragma unroll
            for (int n = 0; n < 4; ++n) {
                int r = wn * 64 + n * 16 + (lane & 15);
                int byte = r * 128 + s * 64 + ((lane >> 4) << 4);
                byte ^= (r & 7) << 4;
                bfr[n] = *(const bf16x8*)(sB + byte);
            }
            #pragma unroll
            for (int m = 0; m < 4; ++m)
                #pragma unroll
                for (int n = 0; n < 4; ++n)
                    acc[m][n] = __builtin_amdgcn_mfma_f32_16x16x32_bf16(
                        af[m], bfr[n], acc[m][n], 0, 0, 0);
        }
        cur ^= 1;
    }
    #undef STAGE_NN

    unsigned short* st = (unsigned short*)sm;
    __syncthreads();
    #pragma unroll
    for (int m = 0; m < 4; ++m)
        #pragma unroll
        for (int n = 0; n < 4; ++n)
            #pragma unroll
            for (int r4 = 0; r4 < 4; ++r4) {
                int jl = wm * 64 + m * 16 + ((lane >> 4) << 2) + r4;
                int nl = wn * 64 + n * 16 + (lane & 15);
                st[jl * 136 + nl] = f2bf(acc[m][n][r4]);
            }
    __syncthreads();
    #pragma unroll
    for (int it = 0; it < 8; ++it) {
        int idx = t + it * 256, jl = idx >> 4, l16 = idx & 15;
        int4 pv = *(int4*)((char*)sm + jl * 272 + l16 * 16);
        *(int4*)(Cg + (size_t)b * cBatch + (size_t)(j0 + jl) * DIMC + n0 + l16 * 8) = pv;
    }
}

// ---------------------------------------------------------------------------
// K3: sumsq via row-dots: sumsq_q[b][j] = dot(T[b][j], Wq[j]);
//     sumsq_k[b][j] = dot(U[b][j], Wk[j]).  TU stacked j in [0,1024).
// ---------------------------------------------------------------------------
__global__ __launch_bounds__(256) void sumsq_dot(
    const unsigned short* __restrict__ TU, const unsigned short* __restrict__ Wb,
    float* __restrict__ sumsq)
{
    const int row  = blockIdx.x * 4 + (threadIdx.x >> 6);   // 0..8191
    const int lane = threadIdx.x & 63;
    const int b = row >> 10, jj = row & 1023;
    Pack8 a, wv;
    a.v  = *(const int4*)(TU + ((size_t)b * 1024 + jj) * DIMC + lane * 8);
    wv.v = *(const int4*)(Wb + (size_t)jj * DIMC + lane * 8);
    float s = 0.f;
    #pragma unroll
    for (int e = 0; e < 8; ++e) s = fmaf(bf2f(a.u[e]), bf2f(wv.u[e]), s);
    #pragma unroll
    for (int o = 32; o > 0; o >>= 1) s += __shfl_down(s, o, 64);
    if (lane == 0)
        sumsq[(jj >> 9) * 4096 + b * DIMC + (jj & 511)] = s;
}

// ---------------------------------------------------------------------------
// K4: fused S + softmax per (b,h):
//   S[r][c] = sum_k T[h*64+r][k] * Wk[h*64+c][k]   (64x64, K=512)
//   attn = softmax_c(S * SCALE * rsq_q[r] * rsq_k[c])
// ---------------------------------------------------------------------------
__global__ __launch_bounds__(256) void s_softmax(
    const unsigned short* __restrict__ TU, const unsigned short* __restrict__ Wb,
    const float* __restrict__ sumsq, float* __restrict__ attn)
{
    const int bh = blockIdx.x;
    const int b = bh >> 3, h = bh & 7;
    const unsigned short* A = TU + ((size_t)b * 1024 + h * 64) * DIMC;   // T rows
    const unsigned short* B = Wb + 262144 + (size_t)(h * 64) * DIMC;     // Wk rows

    __shared__ __align__(16) char sm[32768];   // 2 x (A 8KB + B 8KB)
    __shared__ float sS[64][65];
    __shared__ float srk[64];

    const int t = threadIdx.x, lane = t & 63, w = t >> 6;
    const int wm = w >> 1, wn = w & 1;
    const int rsub = lane >> 3;
    const int srccol = ((lane & 7) ^ rsub) << 3;

    f32x4 zero = {0.f, 0.f, 0.f, 0.f};
    f32x4 acc[2][2];
    #pragma unroll
    for (int m = 0; m < 2; ++m)
        #pragma unroll
        for (int n = 0; n < 2; ++n) acc[m][n] = zero;

    #define STAGE_S(buf, c0)                                                    \
        {                                                                       \
            char* dst = sm + (buf) * 16384;                                     \
            _Pragma("unroll")                                                   \
            for (int i = 0; i < 2; ++i) {                                       \
                int ii = w * 2 + i;                                             \
                gload_lds16(A + (size_t)(ii * 8 + rsub) * DIMC + (c0) + srccol, \
                            dst + ii * 1024);                                   \
                gload_lds16(B + (size_t)(ii * 8 + rsub) * DIMC + (c0) + srccol, \
                            dst + 8192 + ii * 1024);                            \
            }                                                                   \
        }

    STAGE_S(0, 0);
    int cur = 0;
    for (int c0 = 0; c0 < DIMC; c0 += 64) {
        __syncthreads();
        if (c0 + 64 < DIMC) STAGE_S(cur ^ 1, c0 + 64);
        const char* sA = sm + cur * 16384;
        const char* sB = sA + 8192;
        #pragma unroll
        for (int s = 0; s < 2; ++s) {
            bf16x8 aq[2], bk[2];
            #pragma unroll
            for (int m = 0; m < 2; ++m) {
                int r = wm * 32 + m * 16 + (lane & 15);
                int byte = r * 128 + s * 64 + ((lane >> 4) << 4);
                byte ^= (r & 7) << 4;
                aq[m] = *(const bf16x8*)(sA + byte);
            }
            #pragma unroll
            for (int n = 0; n < 2; ++n) {
                int r = wn * 32 + n * 16 + (lane & 15);
                int byte = r * 128 + s * 64 + ((lane >> 4) << 4);
                byte ^= (r & 7) << 4;
                bk[n] = *(const bf16x8*)(sB + byte);
            }
            #pragma unroll
            for (int m = 0; m < 2; ++m)
                #pragma unroll
                for (int n = 0; n < 2; ++n)
                    acc[m][n] = __builtin_amdgcn_mfma_f32_16x16x32_bf16(
                        aq[m], bk[n], acc[m][n], 0, 0, 0);
        }
        cur ^= 1;
    }
    #undef STAGE_S

    // stage S to LDS + rsq_k table, then softmax
    #pragma unroll
    for (int m = 0; m < 2; ++m)
        #pragma unroll
        for (int n = 0; n < 2; ++n)
            #pragma unroll
            for (int r4 = 0; r4 < 4; ++r4) {
                int r = wm * 32 + m * 16 + ((lane >> 4) << 2) + r4;
                int c = wn * 32 + n * 16 + (lane & 15);
                sS[r][c] = acc[m][n][r4];
            }
    if (t < 64)
        srk[t] = 1.0f / fmaxf(sqrtf(sumsq[4096 + b * DIMC + h * 64 + t]), EPSN);
    __syncthreads();

    const int r = t >> 2;       // 0..63
    const int p = t & 3;        // 16-col part
    const float rq = 1.0f / fmaxf(sqrtf(sumsq[b * DIMC + h * 64 + r]), EPSN);
    float row[16];
    #pragma unroll
    for (int c = 0; c < 16; ++c)
        row[c] = sS[r][p * 16 + c] * SCALE * rq * srk[p * 16 + c];
    float mx = row[0];
    #pragma unroll
    for (int c = 1; c < 16; ++c) mx = fmaxf(mx, row[c]);
    mx = fmaxf(mx, __shfl_xor(mx, 1, 4));
    mx = fmaxf(mx, __shfl_xor(mx, 2, 4));
    float sum = 0.f;
    #pragma unroll
    for (int c = 0; c < 16; ++c) { row[c] = __expf(row[c] - mx); sum += row[c]; }
    sum += __shfl_xor(sum, 1, 4);
    sum += __shfl_xor(sum, 2, 4);
    const float inv = 1.0f / sum;
    float* Ao = attn + ((size_t)bh << 12) + r * 64 + p * 16;
    #pragma unroll
    for (int c4 = 0; c4 < 4; ++c4) {
        float4 o = make_float4(row[c4*4+0]*inv, row[c4*4+1]*inv,
                               row[c4*4+2]*inv, row[c4*4+3]*inv);
        *(float4*)(Ao + c4 * 4) = o;
    }
}

// ---------------------------------------------------------------------------
// K5: fold Wp through attn -> Wp2b bf16 [b][j][c]   (unchanged)
// ---------------------------------------------------------------------------
__global__ __launch_bounds__(256) void build_wp2(
    const float* __restrict__ Wp, const float* __restrict__ attn,
    unsigned short* __restrict__ Wp2b)
{
    const int jt = blockIdx.x;
    const int h  = blockIdx.y;
    const int b  = blockIdx.z;

    __shared__ float sA[64][64];
    __shared__ float sW[64][64];

    const int t = threadIdx.x;
    {
        const float* A = attn + ((size_t)(b * 8 + h) << 12);
        for (int i = t * 4; i < 4096; i += 1024)
            *(float4*)&sA[0][i] = *(const float4*)(A + i);
    }
    {
        const int j  = t >> 2;
        const int c0 = (t & 3) * 16;
        #pragma unroll
        for (int i = 0; i < 4; ++i) {
            float4 w4 = *(const float4*)(Wp + (size_t)(jt * 64 + j) * DIMC + h * 64 + c0 + i * 4);
            sW[c0 + i * 4 + 0][j] = w4.x; sW[c0 + i * 4 + 1][j] = w4.y;
            sW[c0 + i * 4 + 2][j] = w4.z; sW[c0 + i * 4 + 3][j] = w4.w;
        }
    }
    __syncthreads();

    const int tx = t & 15, ty = t >> 4;
    float acc[4][4] = {};
    #pragma unroll 16
    for (int c = 0; c < 64; ++c) {
        float wf[4], af[4];
        #pragma unroll
        for (int i = 0; i < 4; ++i) { wf[i] = sW[c][ty * 4 + i]; af[i] = sA[c][tx * 4 + i]; }
        #pragma unroll
        for (int r = 0; r < 4; ++r)
            #pragma unroll
            for (int cc = 0; cc < 4; ++cc)
                acc[r][cc] = fmaf(wf[r], af[cc], acc[r][cc]);
    }

    unsigned short* O = Wp2b + ((size_t)b * DIMC + jt * 64 + ty * 4) * DIMC + h * 64 + tx * 4;
    #pragma unroll
    for (int r = 0; r < 4; ++r) {
        ushort4 o4;
        o4.x = f2bf(acc[r][0]); o4.y = f2bf(acc[r][1]);
        o4.z = f2bf(acc[r][2]); o4.w = f2bf(acc[r][3]);
        *(ushort4*)(O + (size_t)r * DIMC) = o4;
    }
}

// ---------------------------------------------------------------------------
// K6: final GEMM: out[b][j][n] = sum_c3 Wfb[b][j][c3] * xT[b][n][c3]
// (Wf = Wp2 * Wv folded; v never materialized). 128x128, fp32 direct stores.
// ---------------------------------------------------------------------------
__global__ __launch_bounds__(256) void final_mfma(
    const unsigned short* __restrict__ Wfb, const unsigned short* __restrict__ xT,
    float* __restrict__ out)
{
    const int b  = blockIdx.z;
    const int j0 = blockIdx.y * 128;
    const int n0 = blockIdx.x * 128;
    const unsigned short* A = Wfb + (size_t)b * DIMC * DIMC + (size_t)j0 * DIMC;
    const unsigned short* B = xT + (size_t)b * HW * DIMC + (size_t)n0 * DIMC;

    __shared__ __align__(16) char sm[65536];

    const int t = threadIdx.x, lane = t & 63, w = t >> 6;
    const int wm = w >> 1, wn = w & 1;
    const int rsub = lane >> 3;
    const int srccol = ((lane & 7) ^ rsub) << 3;

    f32x4 zero = {0.f, 0.f, 0.f, 0.f};
    f32x4 acc[4][4];
    #pragma unroll
    for (int m = 0; m < 4; ++m)
        #pragma unroll
        for (int n = 0; n < 4; ++n) acc[m][n] = zero;

    #define STAGE_FIN(buf, c0)                                                  \
        {                                                                       \
            char* dst = sm + (buf) * 32768;                                     \
            _Pragma("unroll")                                                   \
            for (int i = 0; i < 4; ++i) {                                       \
                int ii = w * 4 + i;                                             \
                gload_lds16(A + (size_t)(ii * 8 + rsub) * DIMC + (c0) + srccol, \
                            dst + ii * 1024);                                   \
                gload_lds16(B + (size_t)(ii * 8 + rsub) * DIMC + (c0) + srccol, \
                            dst + 16384 + ii * 1024);                           \
            }                                                                   \
        }

    STAGE_FIN(0, 0);
    int cur = 0;
    for (int c0 = 0; c0 < DIMC; c0 += 64) {
        __syncthreads();
        if (c0 + 64 < DIMC) STAGE_FIN(cur ^ 1, c0 + 64);
        const char* sA = sm + cur * 32768;
        const char* sB = sA + 16384;
        #pragma unroll
        for (int s = 0; s < 2; ++s) {
            bf16x8 af[4], bfr[4];
            #pragma unroll
            for (int m = 0; m < 4; ++m) {
                int r = wm * 64 + m * 16 + (lane & 15);
                int byte = r * 128 + s * 64 + ((lane >> 4) << 4);
                byte ^= (r & 7) << 4;
                af[m] = *(const bf16x8*)(sA + byte);
            }
            #pragma unroll
            for (int n = 0; n < 4; ++n) {
                int r = wn * 64 + n * 16 + (lane & 15);
                int byte = r * 128 + s * 64 + ((lane >> 4) << 4);
                byte ^= (r & 7) << 4;
                bfr[n] = *(const bf16x8*)(sB + byte);
            }
            #pragma unroll
            for (int m = 0; m < 4; ++m)
                #pragma unroll
                for (int n = 0; n < 4; ++n)
                    acc[m][n] = __builtin_amdgcn_mfma_f32_16x16x32_bf16(
                        af[m], bfr[n], acc[m][n], 0, 0, 0);
        }
        cur ^= 1;
    }
    #undef STAGE_FIN

    #pragma unroll
    for (int m = 0; m < 4; ++m)
        #pragma unroll
        for (int r4 = 0; r4 < 4; ++r4) {
            int j = j0 + wm * 64 + m * 16 + ((lane >> 4) << 2) + r4;
            size_t rowbase = ((size_t)b * DIMC + j) * HW + n0 + wn * 64 + (lane & 15);
            #pragma unroll
            for (int n = 0; n < 4; ++n)
                out[rowbase + n * 16] = acc[m][n][r4];
        }
}

// ---------------------------------------------------------------------------
// Workspace (bytes):
//   xT    @ 0           67,108,864   [b][n][c] bf16 unmasked
//   xmb   @ 67108864    67,108,864   [b][c][n] bf16 masked
//   Wb    @ 134217728    1,048,576   [Wq|Wk] bf16
//   WvT   @ 135266304      524,288   Wv^T bf16
//   G     @ 135790592    4,194,304   [b][512][512] bf16
//   TU    @ 139984896    8,388,608   [b][1024][512] bf16 (T=WqG | U=WkG)
//   sumsq @ 148373504       32,768   [2][8][512] fp32 (direct-written)
//   attn  @ 148406272    1,048,576   [bh][64][64] fp32
//   Wp2b  @ 149454848    4,194,304   bf16
//   Wfb   @ 153649152    4,194,304   bf16 (Wp2*Wv)
//   Gpart @ 157843456   33,554,432   [4][8][512][512] fp32 split-K partials
//   end ~191.4 MB
// ---------------------------------------------------------------------------
extern "C" void kernel_launch(void* const* d_in, const int* in_sizes, int n_in,
                              void* d_out, int out_size, void* d_ws, size_t ws_size,
                              hipStream_t stream)
{
    const float* x    = (const float*)d_in[0];
    const float* mask = (const float*)d_in[1];
    const float* Wq   = (const float*)d_in[2];
    const float* Wk   = (const float*)d_in[3];
    const float* Wv   = (const float*)d_in[4];
    const float* Wp   = (const float*)d_in[5];
    float* out = (float*)d_out;
    char* wsb = (char*)d_ws;

    unsigned short* xT   = (unsigned short*)(wsb + 0);
    unsigned short* xmb  = (unsigned short*)(wsb + 67108864);
    unsigned short* Wb   = (unsigned short*)(wsb + 134217728);
    unsigned short* WvT  = (unsigned short*)(wsb + 135266304);
    unsigned short* G    = (unsigned short*)(wsb + 135790592);
    unsigned short* TU   = (unsigned short*)(wsb + 139984896);
    float* sumsq         = (float*)(wsb + 148373504);
    float* attn          = (float*)(wsb + 148406272);
    unsigned short* Wp2b = (unsigned short*)(wsb + 149454848);
    unsigned short* Wfb  = (unsigned short*)(wsb + 153649152);
    float* Gpart         = (float*)(wsb + 157843456);

    convert_w  <<<512,             256, 0, stream>>>(Wq, Wk, Wb);
    wvt_conv   <<<dim3(8, 8),      256, 0, stream>>>(Wv, WvT);
    prep_x     <<<dim3(64, 8, 8),  256, 0, stream>>>(x, mask, xT, xmb);
    gram_mfma  <<<dim3(4, 4, 32),  256, 0, stream>>>(xmb, Gpart);
    gram_reduce<<<2048,            256, 0, stream>>>(Gpart, G);
    // TU[b] = [Wq|Wk] (1024x512) * G[b]  (B rows = G rows, valid: G symmetric)
    gemm_nn_128<<<dim3(4, 8, 8),   256, 0, stream>>>(Wb, (size_t)0, G, (size_t)(DIMC*DIMC), TU, (size_t)(1024*DIMC));
    sumsq_dot  <<<2048,            256, 0, stream>>>(TU, Wb, sumsq);
    s_softmax  <<<64,              256, 0, stream>>>(TU, Wb, sumsq, attn);
    build_wp2  <<<dim3(8, 8, 8),   256, 0, stream>>>(Wp, attn, Wp2b);
    // Wfb[b] = Wp2b[b] (512x512) * WvT rows  => Wp2 * Wv
    gemm_nn_128<<<dim3(4, 4, 8),   256, 0, stream>>>(Wp2b, (size_t)(DIMC*DIMC), WvT, (size_t)0, Wfb, (size_t)(DIMC*DIMC));
    final_mfma <<<dim3(32, 4, 8),  256, 0, stream>>>(Wfb, xT, out);
}

// Round 11
// 129.423 us; speedup vs baseline: 1.0358x; 1.0358x over previous
//
#include <hip/hip_runtime.h>
#include <math.h>

#define DIMC 512
#define HW 4096
#define SCALE 0.125f
#define EPSN 1e-12f

typedef __attribute__((ext_vector_type(8))) short bf16x8;
typedef __attribute__((ext_vector_type(4))) float f32x4;

__device__ __forceinline__ unsigned short f2bf(float f) {
    union { float f; unsigned int u; } v; v.f = f;
    unsigned int u = v.u;
    return (unsigned short)((u + 0x7fffu + ((u >> 16) & 1u)) >> 16);
}
__device__ __forceinline__ float bf2f(unsigned short h) {
    union { unsigned int u; float f; } v; v.u = ((unsigned int)h) << 16;
    return v.f;
}

union Pack8 { int4 v; unsigned short u[8]; };

// async global->LDS, 16B per lane, wave-uniform LDS base (HW: base + lane*16)
__device__ __forceinline__ void gload_lds16(const unsigned short* src, char* ldst) {
    __builtin_amdgcn_global_load_lds(
        (const __attribute__((address_space(1))) void*)src,
        (__attribute__((address_space(3))) void*)ldst, 16, 0, 0);
}

// ---------------------------------------------------------------------------
// P1 (merged R11): blocks 0..511: convert Wq,Wk -> Wb bf16 [2][512][512]
//                  blocks 512..575: WvT[c3][c'] = bf16(Wv[c'][c3])
// ---------------------------------------------------------------------------
__global__ __launch_bounds__(256) void prep_w(
    const float* __restrict__ Wq, const float* __restrict__ Wk,
    const float* __restrict__ Wv,
    unsigned short* __restrict__ Wb, unsigned short* __restrict__ WvT)
{
    const int blk = blockIdx.x;
    const int t = threadIdx.x;
    if (blk < 512) {
        int i = (blk * 256 + t) * 4;   // [0, 524288)
        const float* s = (i < 262144) ? Wq : Wk;
        int off = i & 262143;
        float4 v4 = *(const float4*)(s + off);
        ushort4 o;
        o.x = f2bf(v4.x); o.y = f2bf(v4.y); o.z = f2bf(v4.z); o.w = f2bf(v4.w);
        *(ushort4*)(Wb + i) = o;
    } else {
        const int bb = blk - 512;      // 0..63
        const int cp0 = (bb >> 3) * 64;   // c' tile
        const int c30 = (bb & 7) * 64;    // c3 tile
        __shared__ unsigned short sT[64][65];
        #pragma unroll
        for (int i = 0; i < 4; ++i) {
            int ch = t + i * 256;
            int r = ch >> 4, col4 = (ch & 15) * 4;
            float4 v4 = *(const float4*)(Wv + (size_t)(cp0 + r) * DIMC + c30 + col4);
            sT[r][col4 + 0] = f2bf(v4.x); sT[r][col4 + 1] = f2bf(v4.y);
            sT[r][col4 + 2] = f2bf(v4.z); sT[r][col4 + 3] = f2bf(v4.w);
        }
        __syncthreads();
        #pragma unroll
        for (int i = 0; i < 2; ++i) {
            int ch = t + i * 256;
            int n = ch >> 3, cc = (ch & 7) * 8;
            Pack8 pk;
            #pragma unroll
            for (int e = 0; e < 8; ++e) pk.u[e] = sT[cc + e][n];
            *(int4*)(WvT + (size_t)(c30 + n) * DIMC + cp0 + cc) = pk.v;
        }
    }
}

// ---------------------------------------------------------------------------
// P2: prep_x: x[b][c][n] fp32 -> xT[b][n][c] bf16 (unmasked, for final GEMM B)
//                            -> xmb[b][c][n] bf16 masked (for Gram)
// ---------------------------------------------------------------------------
__global__ __launch_bounds__(256) void prep_x(
    const float* __restrict__ x, const float* __restrict__ mask,
    unsigned short* __restrict__ xT, unsigned short* __restrict__ xmb)
{
    const int b  = blockIdx.z;
    const int c0 = blockIdx.y * 64;
    const int n0 = blockIdx.x * 64;
    __shared__ unsigned short sT[64][65];
    const int t = threadIdx.x;
    #pragma unroll
    for (int i = 0; i < 4; ++i) {
        int ch = t + i * 256;
        int r = ch >> 4, col4 = (ch & 15) * 4;
        float4 v4 = *(const float4*)(x + ((size_t)b * DIMC + c0 + r) * HW + n0 + col4);
        sT[r][col4 + 0] = f2bf(v4.x); sT[r][col4 + 1] = f2bf(v4.y);
        sT[r][col4 + 2] = f2bf(v4.z); sT[r][col4 + 3] = f2bf(v4.w);
        float4 mv = *(const float4*)(mask + (size_t)b * HW + n0 + col4);
        ushort4 xm;
        xm.x = f2bf(v4.x * mv.x); xm.y = f2bf(v4.y * mv.y);
        xm.z = f2bf(v4.z * mv.z); xm.w = f2bf(v4.w * mv.w);
        *(ushort4*)(xmb + ((size_t)b * DIMC + c0 + r) * HW + n0 + col4) = xm;
    }
    __syncthreads();
    #pragma unroll
    for (int i = 0; i < 2; ++i) {
        int ch = t + i * 256;
        int n = ch >> 3, cc = (ch & 7) * 8;
        Pack8 pk;
        #pragma unroll
        for (int e = 0; e < 8; ++e) pk.u[e] = sT[cc + e][n];
        *(int4*)(xT + ((size_t)b * HW + n0 + n) * DIMC + c0 + cc) = pk.v;
    }
}

// ---------------------------------------------------------------------------
// K1: Gram GEMM, split-K, bf16 partials (R11): Gpart[sp][b][cA][cB] bf16 =
//       sum_{n in sp*1024..+1024} xmb[cA][n] * xmb[cB][n]
// 128x128 tile, BK=64, dbuf gload_lds. LDS-staged coalesced bf16 stores
// (halves R10's fp32 partial traffic).
// ---------------------------------------------------------------------------
__global__ __launch_bounds__(256) void gram_mfma(
    const unsigned short* __restrict__ xmb, unsigned short* __restrict__ Gpart)
{
    const int b   = blockIdx.z & 7;
    const int sp  = blockIdx.z >> 3;
    const int cA0 = blockIdx.y * 128;
    const int cB0 = blockIdx.x * 128;
    const unsigned short* A = xmb + (size_t)b * DIMC * HW + (size_t)cA0 * HW + sp * 1024;
    const unsigned short* B = xmb + (size_t)b * DIMC * HW + (size_t)cB0 * HW + sp * 1024;

    __shared__ __align__(16) char sm[65536];   // 2 x (A 16KB + B 16KB)

    const int t = threadIdx.x, lane = t & 63, w = t >> 6;
    const int wm = w >> 1, wn = w & 1;
    const int rsub = lane >> 3;
    const int srccol = ((lane & 7) ^ rsub) << 3;

    f32x4 zero = {0.f, 0.f, 0.f, 0.f};
    f32x4 acc[4][4];
    #pragma unroll
    for (int m = 0; m < 4; ++m)
        #pragma unroll
        for (int n = 0; n < 4; ++n) acc[m][n] = zero;

    #define STAGE_G(buf, c0)                                                  \
        {                                                                     \
            char* dst = sm + (buf) * 32768;                                   \
            _Pragma("unroll")                                                 \
            for (int i = 0; i < 4; ++i) {                                     \
                int ii = w * 4 + i;                                           \
                gload_lds16(A + (size_t)(ii * 8 + rsub) * HW + (c0) + srccol, \
                            dst + ii * 1024);                                 \
                gload_lds16(B + (size_t)(ii * 8 + rsub) * HW + (c0) + srccol, \
                            dst + 16384 + ii * 1024);                         \
            }                                                                 \
        }

    STAGE_G(0, 0);
    int cur = 0;
    for (int c0 = 0; c0 < 1024; c0 += 64) {
        __syncthreads();
        if (c0 + 64 < 1024) STAGE_G(cur ^ 1, c0 + 64);
        const char* sA = sm + cur * 32768;
        const char* sB = sA + 16384;
        #pragma unroll
        for (int s = 0; s < 2; ++s) {
            bf16x8 af[4], bfr[4];
            #pragma unroll
            for (int m = 0; m < 4; ++m) {
                int r = wm * 64 + m * 16 + (lane & 15);
                int byte = r * 128 + s * 64 + ((lane >> 4) << 4);
                byte ^= (r & 7) << 4;
                af[m] = *(const bf16x8*)(sA + byte);
            }
            #pragma unroll
            for (int n = 0; n < 4; ++n) {
                int r = wn * 64 + n * 16 + (lane & 15);
                int byte = r * 128 + s * 64 + ((lane >> 4) << 4);
                byte ^= (r & 7) << 4;
                bfr[n] = *(const bf16x8*)(sB + byte);
            }
            #pragma unroll
            for (int m = 0; m < 4; ++m)
                #pragma unroll
                for (int n = 0; n < 4; ++n)
                    acc[m][n] = __builtin_amdgcn_mfma_f32_16x16x32_bf16(
                        af[m], bfr[n], acc[m][n], 0, 0, 0);
        }
        cur ^= 1;
    }
    #undef STAGE_G

    // LDS-staged coalesced bf16 stores [128][128]
    unsigned short* st = (unsigned short*)sm;
    __syncthreads();
    #pragma unroll
    for (int m = 0; m < 4; ++m)
        #pragma unroll
        for (int n = 0; n < 4; ++n)
            #pragma unroll
            for (int r4 = 0; r4 < 4; ++r4) {
                int jl = wm * 64 + m * 16 + ((lane >> 4) << 2) + r4;
                int nl = wn * 64 + n * 16 + (lane & 15);
                st[jl * 136 + nl] = f2bf(acc[m][n][r4]);
            }
    __syncthreads();
    unsigned short* Gp = Gpart + ((size_t)sp * 8 + b) * DIMC * DIMC;
    #pragma unroll
    for (int it = 0; it < 8; ++it) {
        int idx = t + it * 256, jl = idx >> 4, l16 = idx & 15;
        int4 pv = *(int4*)((char*)sm + jl * 272 + l16 * 16);
        *(int4*)(Gp + (size_t)(cA0 + jl) * DIMC + cB0 + l16 * 8) = pv;
    }
}

// ---------------------------------------------------------------------------
// K1b: reduce 4 bf16 split partials -> G bf16 (fp32 accumulate)
// ---------------------------------------------------------------------------
__global__ __launch_bounds__(256) void gram_reduce(
    const unsigned short* __restrict__ Gpart, unsigned short* __restrict__ G)
{
    size_t i = ((size_t)blockIdx.x * 256 + threadIdx.x) * 8;   // over 2,097,152
    Pack8 p0, p1, p2, p3, o;
    p0.v = *(const int4*)(Gpart + i);
    p1.v = *(const int4*)(Gpart + 2097152 + i);
    p2.v = *(const int4*)(Gpart + 4194304 + i);
    p3.v = *(const int4*)(Gpart + 6291456 + i);
    #pragma unroll
    for (int e = 0; e < 8; ++e)
        o.u[e] = f2bf(bf2f(p0.u[e]) + bf2f(p1.u[e]) + bf2f(p2.u[e]) + bf2f(p3.u[e]));
    *(int4*)(G + i) = o.v;
}

// ---------------------------------------------------------------------------
// K2: generic 128x128 NT GEMM, K=512, all row strides 512, bf16 out.
// C[b][j][n] = sum_k A[b][j][k] * B[b][n][k]   (batch strides as args)
// Used for: TU = [Wq|Wk] * G  (B = G rows, valid by G symmetry)
//           Wf = Wp2b * Wv    (B = WvT rows)
// ---------------------------------------------------------------------------
__global__ __launch_bounds__(256) void gemm_nn_128(
    const unsigned short* __restrict__ Ag, size_t aBatch,
    const unsigned short* __restrict__ Bg, size_t bBatch,
    unsigned short* __restrict__ Cg, size_t cBatch)
{
    const int b  = blockIdx.z;
    const int j0 = blockIdx.y * 128;
    const int n0 = blockIdx.x * 128;
    const unsigned short* A = Ag + (size_t)b * aBatch + (size_t)j0 * DIMC;
    const unsigned short* B = Bg + (size_t)b * bBatch + (size_t)n0 * DIMC;

    __shared__ __align__(16) char sm[65536];

    const int t = threadIdx.x, lane = t & 63, w = t >> 6;
    const int wm = w >> 1, wn = w & 1;
    const int rsub = lane >> 3;
    const int srccol = ((lane & 7) ^ rsub) << 3;

    f32x4 zero = {0.f, 0.f, 0.f, 0.f};
    f32x4 acc[4][4];
    #pragma unroll
    for (int m = 0; m < 4; ++m)
        #pragma unroll
        for (int n = 0; n < 4; ++n) acc[m][n] = zero;

    #define STAGE_NN(buf, c0)                                                   \
        {                                                                       \
            char* dst = sm + (buf) * 32768;                                     \
            _Pragma("unroll")                                                   \
            for (int i = 0; i < 4; ++i) {                                       \
                int ii = w * 4 + i;                                             \
                gload_lds16(A + (size_t)(ii * 8 + rsub) * DIMC + (c0) + srccol, \
                            dst + ii * 1024);                                   \
                gload_lds16(B + (size_t)(ii * 8 + rsub) * DIMC + (c0) + srccol, \
                            dst + 16384 + ii * 1024);                           \
            }                                                                   \
        }

    STAGE_NN(0, 0);
    int cur = 0;
    for (int c0 = 0; c0 < DIMC; c0 += 64) {
        __syncthreads();
        if (c0 + 64 < DIMC) STAGE_NN(cur ^ 1, c0 + 64);
        const char* sA = sm + cur * 32768;
        const char* sB = sA + 16384;
        #pragma unroll
        for (int s = 0; s < 2; ++s) {
            bf16x8 af[4], bfr[4];
            #pragma unroll
            for (int m = 0; m < 4; ++m) {
                int r = wm * 64 + m * 16 + (lane & 15);
                int byte = r * 128 + s * 64 + ((lane >> 4) << 4);
                byte ^= (r & 7) << 4;
                af[m] = *(const bf16x8*)(sA + byte);
            }
            #pragma unroll
            for (int n = 0; n < 4; ++n) {
                int r = wn * 64 + n * 16 + (lane & 15);
                int byte = r * 128 + s * 64 + ((lane >> 4) << 4);
                byte ^= (r & 7) << 4;
                bfr[n] = *(const bf16x8*)(sB + byte);
            }
            #pragma unroll
            for (int m = 0; m < 4; ++m)
                #pragma unroll
                for (int n = 0; n < 4; ++n)
                    acc[m][n] = __builtin_amdgcn_mfma_f32_16x16x32_bf16(
                        af[m], bfr[n], acc[m][n], 0, 0, 0);
        }
        cur ^= 1;
    }
    #undef STAGE_NN

    unsigned short* st = (unsigned short*)sm;
    __syncthreads();
    #pragma unroll
    for (int m = 0; m < 4; ++m)
        #pragma unroll
        for (int n = 0; n < 4; ++n)
            #pragma unroll
            for (int r4 = 0; r4 < 4; ++r4) {
                int jl = wm * 64 + m * 16 + ((lane >> 4) << 2) + r4;
                int nl = wn * 64 + n * 16 + (lane & 15);
                st[jl * 136 + nl] = f2bf(acc[m][n][r4]);
            }
    __syncthreads();
    #pragma unroll
    for (int it = 0; it < 8; ++it) {
        int idx = t + it * 256, jl = idx >> 4, l16 = idx & 15;
        int4 pv = *(int4*)((char*)sm + jl * 272 + l16 * 16);
        *(int4*)(Cg + (size_t)b * cBatch + (size_t)(j0 + jl) * DIMC + n0 + l16 * 8) = pv;
    }
}

// ---------------------------------------------------------------------------
// K4: fused rsq + S + softmax per (b,h) (R11: sumsq_dot folded in):
//   srq[r] = 1/max(sqrt(dot(T[h*64+r], Wq[h*64+r])), eps)
//   srk[c] = 1/max(sqrt(dot(U[h*64+c], Wk[h*64+c])), eps)
//   S[r][c] = sum_k T[h*64+r][k] * Wk[h*64+c][k]   (64x64, K=512)
//   attn = softmax_c(S * SCALE * srq[r] * srk[c])
// ---------------------------------------------------------------------------
__global__ __launch_bounds__(256) void s_softmax(
    const unsigned short* __restrict__ TU, const unsigned short* __restrict__ Wb,
    float* __restrict__ attn)
{
    const int bh = blockIdx.x;
    const int b = bh >> 3, h = bh & 7;
    const unsigned short* A = TU + ((size_t)b * 1024 + h * 64) * DIMC;   // T rows
    const unsigned short* B = Wb + 262144 + (size_t)(h * 64) * DIMC;     // Wk rows

    __shared__ __align__(16) char sm[32768];   // 2 x (A 8KB + B 8KB)
    __shared__ float sS[64][65];
    __shared__ float srq[64];
    __shared__ float srk[64];

    const int t = threadIdx.x, lane = t & 63, w = t >> 6;
    const int wm = w >> 1, wn = w & 1;
    const int rsub = lane >> 3;
    const int srccol = ((lane & 7) ^ rsub) << 3;

    // ---- fused row-dots: 128 rows (64 q from T/Wq, 64 k from U/Wk), 2 thr/row
    {
        const int rid  = t >> 1;        // 0..127
        const int half = t & 1;
        const int isK  = (rid >= 64);
        const int rl   = rid & 63;
        const unsigned short* ar = TU + ((size_t)b * 1024 + (isK ? 512 : 0) + h * 64 + rl) * DIMC
                                 + half * 256;
        const unsigned short* wr = Wb + (isK ? 262144 : 0) + (size_t)(h * 64 + rl) * DIMC
                                 + half * 256;
        float s = 0.f;
        #pragma unroll 8
        for (int i = 0; i < 32; ++i) {
            Pack8 pa, pw;
            pa.v = *(const int4*)(ar + i * 8);
            pw.v = *(const int4*)(wr + i * 8);
            #pragma unroll
            for (int e = 0; e < 8; ++e) s = fmaf(bf2f(pa.u[e]), bf2f(pw.u[e]), s);
        }
        s += __shfl_xor(s, 1, 2);
        if (half == 0) {
            float r = 1.0f / fmaxf(sqrtf(s), EPSN);
            if (isK) srk[rl] = r; else srq[rl] = r;
        }
    }

    f32x4 zero = {0.f, 0.f, 0.f, 0.f};
    f32x4 acc[2][2];
    #pragma unroll
    for (int m = 0; m < 2; ++m)
        #pragma unroll
        for (int n = 0; n < 2; ++n) acc[m][n] = zero;

    #define STAGE_S(buf, c0)                                                    \
        {                                                                       \
            char* dst = sm + (buf) * 16384;                                     \
            _Pragma("unroll")                                                   \
            for (int i = 0; i < 2; ++i) {                                       \
                int ii = w * 2 + i;                                             \
                gload_lds16(A + (size_t)(ii * 8 + rsub) * DIMC + (c0) + srccol, \
                            dst + ii * 1024);                                   \
                gload_lds16(B + (size_t)(ii * 8 + rsub) * DIMC + (c0) + srccol, \
                            dst + 8192 + ii * 1024);                            \
            }                                                                   \
        }

    STAGE_S(0, 0);
    int cur = 0;
    for (int c0 = 0; c0 < DIMC; c0 += 64) {
        __syncthreads();
        if (c0 + 64 < DIMC) STAGE_S(cur ^ 1, c0 + 64);
        const char* sA = sm + cur * 16384;
        const char* sB = sA + 8192;
        #pragma unroll
        for (int s = 0; s < 2; ++s) {
            bf16x8 aq[2], bk[2];
            #pragma unroll
            for (int m = 0; m < 2; ++m) {
                int r = wm * 32 + m * 16 + (lane & 15);
                int byte = r * 128 + s * 64 + ((lane >> 4) << 4);
                byte ^= (r & 7) << 4;
                aq[m] = *(const bf16x8*)(sA + byte);
            }
            #pragma unroll
            for (int n = 0; n < 2; ++n) {
                int r = wn * 32 + n * 16 + (lane & 15);
                int byte = r * 128 + s * 64 + ((lane >> 4) << 4);
                byte ^= (r & 7) << 4;
                bk[n] = *(const bf16x8*)(sB + byte);
            }
            #pragma unroll
            for (int m = 0; m < 2; ++m)
                #pragma unroll
                for (int n = 0; n < 2; ++n)
                    acc[m][n] = __builtin_amdgcn_mfma_f32_16x16x32_bf16(
                        aq[m], bk[n], acc[m][n], 0, 0, 0);
        }
        cur ^= 1;
    }
    #undef STAGE_S

    // stage S to LDS, then softmax
    #pragma unroll
    for (int m = 0; m < 2; ++m)
        #pragma unroll
        for (int n = 0; n < 2; ++n)
            #pragma unroll
            for (int r4 = 0; r4 < 4; ++r4) {
                int r = wm * 32 + m * 16 + ((lane >> 4) << 2) + r4;
                int c = wn * 32 + n * 16 + (lane & 15);
                sS[r][c] = acc[m][n][r4];
            }
    __syncthreads();

    const int r = t >> 2;       // 0..63
    const int p = t & 3;        // 16-col part
    const float rq = srq[r];
    float row[16];
    #pragma unroll
    for (int c = 0; c < 16; ++c)
        row[c] = sS[r][p * 16 + c] * SCALE * rq * srk[p * 16 + c];
    float mx = row[0];
    #pragma unroll
    for (int c = 1; c < 16; ++c) mx = fmaxf(mx, row[c]);
    mx = fmaxf(mx, __shfl_xor(mx, 1, 4));
    mx = fmaxf(mx, __shfl_xor(mx, 2, 4));
    float sum = 0.f;
    #pragma unroll
    for (int c = 0; c < 16; ++c) { row[c] = __expf(row[c] - mx); sum += row[c]; }
    sum += __shfl_xor(sum, 1, 4);
    sum += __shfl_xor(sum, 2, 4);
    const float inv = 1.0f / sum;
    float* Ao = attn + ((size_t)bh << 12) + r * 64 + p * 16;
    #pragma unroll
    for (int c4 = 0; c4 < 4; ++c4) {
        float4 o = make_float4(row[c4*4+0]*inv, row[c4*4+1]*inv,
                               row[c4*4+2]*inv, row[c4*4+3]*inv);
        *(float4*)(Ao + c4 * 4) = o;
    }
}

// ---------------------------------------------------------------------------
// K5: fold Wp through attn -> Wp2b bf16 [b][j][c]   (unchanged)
// ---------------------------------------------------------------------------
__global__ __launch_bounds__(256) void build_wp2(
    const float* __restrict__ Wp, const float* __restrict__ attn,
    unsigned short* __restrict__ Wp2b)
{
    const int jt = blockIdx.x;
    const int h  = blockIdx.y;
    const int b  = blockIdx.z;

    __shared__ float sA[64][64];
    __shared__ float sW[64][64];

    const int t = threadIdx.x;
    {
        const float* A = attn + ((size_t)(b * 8 + h) << 12);
        for (int i = t * 4; i < 4096; i += 1024)
            *(float4*)&sA[0][i] = *(const float4*)(A + i);
    }
    {
        const int j  = t >> 2;
        const int c0 = (t & 3) * 16;
        #pragma unroll
        for (int i = 0; i < 4; ++i) {
            float4 w4 = *(const float4*)(Wp + (size_t)(jt * 64 + j) * DIMC + h * 64 + c0 + i * 4);
            sW[c0 + i * 4 + 0][j] = w4.x; sW[c0 + i * 4 + 1][j] = w4.y;
            sW[c0 + i * 4 + 2][j] = w4.z; sW[c0 + i * 4 + 3][j] = w4.w;
        }
    }
    __syncthreads();

    const int tx = t & 15, ty = t >> 4;
    float acc[4][4] = {};
    #pragma unroll 16
    for (int c = 0; c < 64; ++c) {
        float wf[4], af[4];
        #pragma unroll
        for (int i = 0; i < 4; ++i) { wf[i] = sW[c][ty * 4 + i]; af[i] = sA[c][tx * 4 + i]; }
        #pragma unroll
        for (int r = 0; r < 4; ++r)
            #pragma unroll
            for (int cc = 0; cc < 4; ++cc)
                acc[r][cc] = fmaf(wf[r], af[cc], acc[r][cc]);
    }

    unsigned short* O = Wp2b + ((size_t)b * DIMC + jt * 64 + ty * 4) * DIMC + h * 64 + tx * 4;
    #pragma unroll
    for (int r = 0; r < 4; ++r) {
        ushort4 o4;
        o4.x = f2bf(acc[r][0]); o4.y = f2bf(acc[r][1]);
        o4.z = f2bf(acc[r][2]); o4.w = f2bf(acc[r][3]);
        *(ushort4*)(O + (size_t)r * DIMC) = o4;
    }
}

// ---------------------------------------------------------------------------
// K6: final GEMM: out[b][j][n] = sum_c3 Wfb[b][j][c3] * xT[b][n][c3]
// (Wf = Wp2 * Wv folded; v never materialized). 128x128, fp32 direct stores.
// ---------------------------------------------------------------------------
__global__ __launch_bounds__(256) void final_mfma(
    const unsigned short* __restrict__ Wfb, const unsigned short* __restrict__ xT,
    float* __restrict__ out)
{
    const int b  = blockIdx.z;
    const int j0 = blockIdx.y * 128;
    const int n0 = blockIdx.x * 128;
    const unsigned short* A = Wfb + (size_t)b * DIMC * DIMC + (size_t)j0 * DIMC;
    const unsigned short* B = xT + (size_t)b * HW * DIMC + (size_t)n0 * DIMC;

    __shared__ __align__(16) char sm[65536];

    const int t = threadIdx.x, lane = t & 63, w = t >> 6;
    const int wm = w >> 1, wn = w & 1;
    const int rsub = lane >> 3;
    const int srccol = ((lane & 7) ^ rsub) << 3;

    f32x4 zero = {0.f, 0.f, 0.f, 0.f};
    f32x4 acc[4][4];
    #pragma unroll
    for (int m = 0; m < 4; ++m)
        #pragma unroll
        for (int n = 0; n < 4; ++n) acc[m][n] = zero;

    #define STAGE_FIN(buf, c0)                                                  \
        {                                                                       \
            char* dst = sm + (buf) * 32768;                                     \
            _Pragma("unroll")                                                   \
            for (int i = 0; i < 4; ++i) {                                       \
                int ii = w * 4 + i;                                             \
                gload_lds16(A + (size_t)(ii * 8 + rsub) * DIMC + (c0) + srccol, \
                            dst + ii * 1024);                                   \
                gload_lds16(B + (size_t)(ii * 8 + rsub) * DIMC + (c0) + srccol, \
                            dst + 16384 + ii * 1024);                           \
            }                                                                   \
        }

    STAGE_FIN(0, 0);
    int cur = 0;
    for (int c0 = 0; c0 < DIMC; c0 += 64) {
        __syncthreads();
        if (c0 + 64 < DIMC) STAGE_FIN(cur ^ 1, c0 + 64);
        const char* sA = sm + cur * 32768;
        const char* sB = sA + 16384;
        #pragma unroll
        for (int s = 0; s < 2; ++s) {
            bf16x8 af[4], bfr[4];
            #pragma unroll
            for (int m = 0; m < 4; ++m) {
                int r = wm * 64 + m * 16 + (lane & 15);
                int byte = r * 128 + s * 64 + ((lane >> 4) << 4);
                byte ^= (r & 7) << 4;
                af[m] = *(const bf16x8*)(sA + byte);
            }
            #pragma unroll
            for (int n = 0; n < 4; ++n) {
                int r = wn * 64 + n * 16 + (lane & 15);
                int byte = r * 128 + s * 64 + ((lane >> 4) << 4);
                byte ^= (r & 7) << 4;
                bfr[n] = *(const bf16x8*)(sB + byte);
            }
            #pragma unroll
            for (int m = 0; m < 4; ++m)
                #pragma unroll
                for (int n = 0; n < 4; ++n)
                    acc[m][n] = __builtin_amdgcn_mfma_f32_16x16x32_bf16(
                        af[m], bfr[n], acc[m][n], 0, 0, 0);
        }
        cur ^= 1;
    }
    #undef STAGE_FIN

    #pragma unroll
    for (int m = 0; m < 4; ++m)
        #pragma unroll
        for (int r4 = 0; r4 < 4; ++r4) {
            int j = j0 + wm * 64 + m * 16 + ((lane >> 4) << 2) + r4;
            size_t rowbase = ((size_t)b * DIMC + j) * HW + n0 + wn * 64 + (lane & 15);
            #pragma unroll
            for (int n = 0; n < 4; ++n)
                out[rowbase + n * 16] = acc[m][n][r4];
        }
}

// ---------------------------------------------------------------------------
// Workspace (bytes):
//   xT    @ 0           67,108,864   [b][n][c] bf16 unmasked
//   xmb   @ 67108864    67,108,864   [b][c][n] bf16 masked
//   Wb    @ 134217728    1,048,576   [Wq|Wk] bf16
//   WvT   @ 135266304      524,288   Wv^T bf16
//   G     @ 135790592    4,194,304   [b][512][512] bf16
//   TU    @ 139984896    8,388,608   [b][1024][512] bf16 (T=WqG | U=WkG)
//   attn  @ 148406272    1,048,576   [bh][64][64] fp32
//   Wp2b  @ 149454848    4,194,304   bf16
//   Wfb   @ 153649152    4,194,304   bf16 (Wp2*Wv)
//   Gpart @ 157843456   16,777,216   [4][8][512][512] bf16 split-K partials
//   end ~174.6 MB
// ---------------------------------------------------------------------------
extern "C" void kernel_launch(void* const* d_in, const int* in_sizes, int n_in,
                              void* d_out, int out_size, void* d_ws, size_t ws_size,
                              hipStream_t stream)
{
    const float* x    = (const float*)d_in[0];
    const float* mask = (const float*)d_in[1];
    const float* Wq   = (const float*)d_in[2];
    const float* Wk   = (const float*)d_in[3];
    const float* Wv   = (const float*)d_in[4];
    const float* Wp   = (const float*)d_in[5];
    float* out = (float*)d_out;
    char* wsb = (char*)d_ws;

    unsigned short* xT   = (unsigned short*)(wsb + 0);
    unsigned short* xmb  = (unsigned short*)(wsb + 67108864);
    unsigned short* Wb   = (unsigned short*)(wsb + 134217728);
    unsigned short* WvT  = (unsigned short*)(wsb + 135266304);
    unsigned short* G    = (unsigned short*)(wsb + 135790592);
    unsigned short* TU   = (unsigned short*)(wsb + 139984896);
    float* attn          = (float*)(wsb + 148406272);
    unsigned short* Wp2b = (unsigned short*)(wsb + 149454848);
    unsigned short* Wfb  = (unsigned short*)(wsb + 153649152);
    unsigned short* Gpart= (unsigned short*)(wsb + 157843456);

    prep_w     <<<576,             256, 0, stream>>>(Wq, Wk, Wv, Wb, WvT);
    prep_x     <<<dim3(64, 8, 8),  256, 0, stream>>>(x, mask, xT, xmb);
    gram_mfma  <<<dim3(4, 4, 32),  256, 0, stream>>>(xmb, Gpart);
    gram_reduce<<<1024,            256, 0, stream>>>(Gpart, G);
    // TU[b] = [Wq|Wk] (1024x512) * G[b]  (B rows = G rows, valid: G symmetric)
    gemm_nn_128<<<dim3(4, 8, 8),   256, 0, stream>>>(Wb, (size_t)0, G, (size_t)(DIMC*DIMC), TU, (size_t)(1024*DIMC));
    s_softmax  <<<64,              256, 0, stream>>>(TU, Wb, attn);
    build_wp2  <<<dim3(8, 8, 8),   256, 0, stream>>>(Wp, attn, Wp2b);
    // Wfb[b] = Wp2b[b] (512x512) * WvT rows  => Wp2 * Wv
    gemm_nn_128<<<dim3(4, 4, 8),   256, 0, stream>>>(Wp2b, (size_t)(DIMC*DIMC), WvT, (size_t)0, Wfb, (size_t)(DIMC*DIMC));
    final_mfma <<<dim3(32, 4, 8),  256, 0, stream>>>(Wfb, xT, out);
}

// Round 12
// 114.850 us; speedup vs baseline: 1.1673x; 1.1269x over previous
//
#include <hip/hip_runtime.h>
#include <math.h>

#define DIMC 512
#define HW 4096
#define SCALE 0.125f
#define EPSN 1e-12f

typedef __attribute__((ext_vector_type(8))) short bf16x8;
typedef __attribute__((ext_vector_type(4))) float f32x4;

__device__ __forceinline__ unsigned short f2bf(float f) {
    union { float f; unsigned int u; } v; v.f = f;
    unsigned int u = v.u;
    return (unsigned short)((u + 0x7fffu + ((u >> 16) & 1u)) >> 16);
}
__device__ __forceinline__ float bf2f(unsigned short h) {
    union { unsigned int u; float f; } v; v.u = ((unsigned int)h) << 16;
    return v.f;
}

union Pack8 { int4 v; unsigned short u[8]; };

__device__ __forceinline__ void gload_lds16(const unsigned short* src, char* ldst) {
    __builtin_amdgcn_global_load_lds(
        (const __attribute__((address_space(1))) void*)src,
        (__attribute__((address_space(3))) void*)ldst, 16, 0, 0);
}

// ---------------------------------------------------------------------------
// P1 (R12, all prep merged): blocks 0..511   : Wq,Wk -> Wb bf16
//                            blocks 512..575 : WvT = bf16(Wv^T)
//                            blocks 576..831 : Wp -> Wpb bf16
//                            blocks 832..4927: prep_x (xT + xmb)
// ---------------------------------------------------------------------------
__global__ __launch_bounds__(256) void prep_wx(
    const float* __restrict__ Wq, const float* __restrict__ Wk,
    const float* __restrict__ Wv, const float* __restrict__ Wp,
    const float* __restrict__ x, const float* __restrict__ mask,
    unsigned short* __restrict__ Wb, unsigned short* __restrict__ WvT,
    unsigned short* __restrict__ Wpb,
    unsigned short* __restrict__ xT, unsigned short* __restrict__ xmb)
{
    const int blk = blockIdx.x;
    const int t = threadIdx.x;
    if (blk < 512) {
        int i = (blk * 256 + t) * 4;
        const float* s = (i < 262144) ? Wq : Wk;
        int off = i & 262143;
        float4 v4 = *(const float4*)(s + off);
        ushort4 o;
        o.x = f2bf(v4.x); o.y = f2bf(v4.y); o.z = f2bf(v4.z); o.w = f2bf(v4.w);
        *(ushort4*)(Wb + i) = o;
    } else if (blk < 576) {
        const int bb = blk - 512;
        const int cp0 = (bb >> 3) * 64;
        const int c30 = (bb & 7) * 64;
        __shared__ unsigned short sT[64][65];
        #pragma unroll
        for (int i = 0; i < 4; ++i) {
            int ch = t + i * 256;
            int r = ch >> 4, col4 = (ch & 15) * 4;
            float4 v4 = *(const float4*)(Wv + (size_t)(cp0 + r) * DIMC + c30 + col4);
            sT[r][col4 + 0] = f2bf(v4.x); sT[r][col4 + 1] = f2bf(v4.y);
            sT[r][col4 + 2] = f2bf(v4.z); sT[r][col4 + 3] = f2bf(v4.w);
        }
        __syncthreads();
        #pragma unroll
        for (int i = 0; i < 2; ++i) {
            int ch = t + i * 256;
            int n = ch >> 3, cc = (ch & 7) * 8;
            Pack8 pk;
            #pragma unroll
            for (int e = 0; e < 8; ++e) pk.u[e] = sT[cc + e][n];
            *(int4*)(WvT + (size_t)(c30 + n) * DIMC + cp0 + cc) = pk.v;
        }
    } else if (blk < 832) {
        int i = ((blk - 576) * 256 + t) * 4;   // [0, 262144)
        float4 v4 = *(const float4*)(Wp + i);
        ushort4 o;
        o.x = f2bf(v4.x); o.y = f2bf(v4.y); o.z = f2bf(v4.z); o.w = f2bf(v4.w);
        *(ushort4*)(Wpb + i) = o;
    } else {
        const int idx = blk - 832;
        const int n0 = (idx & 63) * 64;
        const int c0 = ((idx >> 6) & 7) * 64;
        const int b  = idx >> 9;
        __shared__ unsigned short sT[64][65];
        #pragma unroll
        for (int i = 0; i < 4; ++i) {
            int ch = t + i * 256;
            int r = ch >> 4, col4 = (ch & 15) * 4;
            float4 v4 = *(const float4*)(x + ((size_t)b * DIMC + c0 + r) * HW + n0 + col4);
            sT[r][col4 + 0] = f2bf(v4.x); sT[r][col4 + 1] = f2bf(v4.y);
            sT[r][col4 + 2] = f2bf(v4.z); sT[r][col4 + 3] = f2bf(v4.w);
            float4 mv = *(const float4*)(mask + (size_t)b * HW + n0 + col4);
            ushort4 xm;
            xm.x = f2bf(v4.x * mv.x); xm.y = f2bf(v4.y * mv.y);
            xm.z = f2bf(v4.z * mv.z); xm.w = f2bf(v4.w * mv.w);
            *(ushort4*)(xmb + ((size_t)b * DIMC + c0 + r) * HW + n0 + col4) = xm;
        }
        __syncthreads();
        #pragma unroll
        for (int i = 0; i < 2; ++i) {
            int ch = t + i * 256;
            int n = ch >> 3, cc = (ch & 7) * 8;
            Pack8 pk;
            #pragma unroll
            for (int e = 0; e < 8; ++e) pk.u[e] = sT[cc + e][n];
            *(int4*)(xT + ((size_t)b * HW + n0 + n) * DIMC + c0 + cc) = pk.v;
        }
    }
}

// ---------------------------------------------------------------------------
// K1: TRIANGULAR Gram GEMM, split-K (R12): G symmetric -> only 10 of 16
// 128x128 tiles (ta<=tb). Gpart compact: [(sp*8+b)*10 + pair][128][128] bf16.
// ---------------------------------------------------------------------------
__global__ __launch_bounds__(256) void gram_mfma(
    const unsigned short* __restrict__ xmb, unsigned short* __restrict__ Gpart)
{
    const int pair = blockIdx.x;          // 0..9
    const int sp   = blockIdx.y >> 3;     // 0..3
    const int b    = blockIdx.y & 7;
    const int TA[10] = {0,0,0,0,1,1,1,2,2,3};
    const int TB[10] = {0,1,2,3,1,2,3,2,3,3};
    const int cA0 = TA[pair] * 128;
    const int cB0 = TB[pair] * 128;
    const unsigned short* A = xmb + (size_t)b * DIMC * HW + (size_t)cA0 * HW + sp * 1024;
    const unsigned short* B = xmb + (size_t)b * DIMC * HW + (size_t)cB0 * HW + sp * 1024;

    __shared__ __align__(16) char sm[65536];

    const int t = threadIdx.x, lane = t & 63, w = t >> 6;
    const int wm = w >> 1, wn = w & 1;
    const int rsub = lane >> 3;
    const int srccol = ((lane & 7) ^ rsub) << 3;

    f32x4 zero = {0.f, 0.f, 0.f, 0.f};
    f32x4 acc[4][4];
    #pragma unroll
    for (int m = 0; m < 4; ++m)
        #pragma unroll
        for (int n = 0; n < 4; ++n) acc[m][n] = zero;

    #define STAGE_G(buf, c0)                                                  \
        {                                                                     \
            char* dst = sm + (buf) * 32768;                                   \
            _Pragma("unroll")                                                 \
            for (int i = 0; i < 4; ++i) {                                     \
                int ii = w * 4 + i;                                           \
                gload_lds16(A + (size_t)(ii * 8 + rsub) * HW + (c0) + srccol, \
                            dst + ii * 1024);                                 \
                gload_lds16(B + (size_t)(ii * 8 + rsub) * HW + (c0) + srccol, \
                            dst + 16384 + ii * 1024);                         \
            }                                                                 \
        }

    STAGE_G(0, 0);
    int cur = 0;
    for (int c0 = 0; c0 < 1024; c0 += 64) {
        __syncthreads();
        if (c0 + 64 < 1024) STAGE_G(cur ^ 1, c0 + 64);
        const char* sA = sm + cur * 32768;
        const char* sB = sA + 16384;
        #pragma unroll
        for (int s = 0; s < 2; ++s) {
            bf16x8 af[4], bfr[4];
            #pragma unroll
            for (int m = 0; m < 4; ++m) {
                int r = wm * 64 + m * 16 + (lane & 15);
                int byte = r * 128 + s * 64 + ((lane >> 4) << 4);
                byte ^= (r & 7) << 4;
                af[m] = *(const bf16x8*)(sA + byte);
            }
            #pragma unroll
            for (int n = 0; n < 4; ++n) {
                int r = wn * 64 + n * 16 + (lane & 15);
                int byte = r * 128 + s * 64 + ((lane >> 4) << 4);
                byte ^= (r & 7) << 4;
                bfr[n] = *(const bf16x8*)(sB + byte);
            }
            #pragma unroll
            for (int m = 0; m < 4; ++m)
                #pragma unroll
                for (int n = 0; n < 4; ++n)
                    acc[m][n] = __builtin_amdgcn_mfma_f32_16x16x32_bf16(
                        af[m], bfr[n], acc[m][n], 0, 0, 0);
        }
        cur ^= 1;
    }
    #undef STAGE_G

    // LDS-staged coalesced bf16 store, compact [128][128]
    unsigned short* st = (unsigned short*)sm;
    __syncthreads();
    #pragma unroll
    for (int m = 0; m < 4; ++m)
        #pragma unroll
        for (int n = 0; n < 4; ++n)
            #pragma unroll
            for (int r4 = 0; r4 < 4; ++r4) {
                int jl = wm * 64 + m * 16 + ((lane >> 4) << 2) + r4;
                int nl = wn * 64 + n * 16 + (lane & 15);
                st[jl * 136 + nl] = f2bf(acc[m][n][r4]);
            }
    __syncthreads();
    unsigned short* Gp = Gpart + ((size_t)(sp * 8 + b) * 10 + pair) * 16384;
    #pragma unroll
    for (int it = 0; it < 8; ++it) {
        int idx = t + it * 256, jl = idx >> 4, l16 = idx & 15;
        int4 pv = *(int4*)((char*)sm + jl * 272 + l16 * 16);
        *(int4*)(Gp + (size_t)jl * 128 + l16 * 8) = pv;
    }
}

// ---------------------------------------------------------------------------
// K1b: reduce 4 split partials of each (pair,b) tile -> G[512][512] bf16,
// writing BOTH the tile and its transposed mirror (G symmetric).
// grid (10 pairs, 8 b)
// ---------------------------------------------------------------------------
__global__ __launch_bounds__(256) void gram_reduce_sym(
    const unsigned short* __restrict__ Gpart, unsigned short* __restrict__ G)
{
    const int pair = blockIdx.x;
    const int b    = blockIdx.y;
    const int TA[10] = {0,0,0,0,1,1,1,2,2,3};
    const int TB[10] = {0,1,2,3,1,2,3,2,3,3};
    const int ta = TA[pair], tb = TB[pair];
    const int t = threadIdx.x;

    __shared__ unsigned short sT[128][130];
    unsigned short* Gb = G + (size_t)b * DIMC * DIMC;

    #pragma unroll
    for (int ch = 0; ch < 8; ++ch) {
        int e = ch * 2048 + t * 8;            // elem index within 128x128 tile
        int i = e >> 7, j = e & 127;
        Pack8 p0, p1, p2, p3, o;
        p0.v = *(const int4*)(Gpart + ((size_t)(0 * 8 + b) * 10 + pair) * 16384 + e);
        p1.v = *(const int4*)(Gpart + ((size_t)(1 * 8 + b) * 10 + pair) * 16384 + e);
        p2.v = *(const int4*)(Gpart + ((size_t)(2 * 8 + b) * 10 + pair) * 16384 + e);
        p3.v = *(const int4*)(Gpart + ((size_t)(3 * 8 + b) * 10 + pair) * 16384 + e);
        #pragma unroll
        for (int k = 0; k < 8; ++k) {
            unsigned short s = f2bf(bf2f(p0.u[k]) + bf2f(p1.u[k]) + bf2f(p2.u[k]) + bf2f(p3.u[k]));
            o.u[k] = s;
            sT[i][j + k] = s;
        }
        *(int4*)(Gb + (size_t)(ta * 128 + i) * DIMC + tb * 128 + j) = o.v;
    }
    if (ta != tb) {
        __syncthreads();
        #pragma unroll
        for (int ch = 0; ch < 8; ++ch) {
            int e = ch * 2048 + t * 8;
            int i2 = e >> 7, j2 = e & 127;    // row/col of the MIRROR tile
            Pack8 o;
            #pragma unroll
            for (int k = 0; k < 8; ++k) o.u[k] = sT[j2 + k][i2];
            *(int4*)(Gb + (size_t)(tb * 128 + i2) * DIMC + ta * 128 + j2) = o.v;
        }
    }
}

// ---------------------------------------------------------------------------
// K2: generic 128x128 NT GEMM, K=512, row stride 512, bf16 out.
// Used for: TU = [Wq|Wk] * G ; Wfb = Wp2b * WvT
// ---------------------------------------------------------------------------
__global__ __launch_bounds__(256) void gemm_nn_128(
    const unsigned short* __restrict__ Ag, size_t aBatch,
    const unsigned short* __restrict__ Bg, size_t bBatch,
    unsigned short* __restrict__ Cg, size_t cBatch)
{
    const int b  = blockIdx.z;
    const int j0 = blockIdx.y * 128;
    const int n0 = blockIdx.x * 128;
    const unsigned short* A = Ag + (size_t)b * aBatch + (size_t)j0 * DIMC;
    const unsigned short* B = Bg + (size_t)b * bBatch + (size_t)n0 * DIMC;

    __shared__ __align__(16) char sm[65536];

    const int t = threadIdx.x, lane = t & 63, w = t >> 6;
    const int wm = w >> 1, wn = w & 1;
    const int rsub = lane >> 3;
    const int srccol = ((lane & 7) ^ rsub) << 3;

    f32x4 zero = {0.f, 0.f, 0.f, 0.f};
    f32x4 acc[4][4];
    #pragma unroll
    for (int m = 0; m < 4; ++m)
        #pragma unroll
        for (int n = 0; n < 4; ++n) acc[m][n] = zero;

    #define STAGE_NN(buf, c0)                                                   \
        {                                                                       \
            char* dst = sm + (buf) * 32768;                                     \
            _Pragma("unroll")                                                   \
            for (int i = 0; i < 4; ++i) {                                       \
                int ii = w * 4 + i;                                             \
                gload_lds16(A + (size_t)(ii * 8 + rsub) * DIMC + (c0) + srccol, \
                            dst + ii * 1024);                                   \
                gload_lds16(B + (size_t)(ii * 8 + rsub) * DIMC + (c0) + srccol, \
                            dst + 16384 + ii * 1024);                           \
            }                                                                   \
        }

    STAGE_NN(0, 0);
    int cur = 0;
    for (int c0 = 0; c0 < DIMC; c0 += 64) {
        __syncthreads();
        if (c0 + 64 < DIMC) STAGE_NN(cur ^ 1, c0 + 64);
        const char* sA = sm + cur * 32768;
        const char* sB = sA + 16384;
        #pragma unroll
        for (int s = 0; s < 2; ++s) {
            bf16x8 af[4], bfr[4];
            #pragma unroll
            for (int m = 0; m < 4; ++m) {
                int r = wm * 64 + m * 16 + (lane & 15);
                int byte = r * 128 + s * 64 + ((lane >> 4) << 4);
                byte ^= (r & 7) << 4;
                af[m] = *(const bf16x8*)(sA + byte);
            }
            #pragma unroll
            for (int n = 0; n < 4; ++n) {
                int r = wn * 64 + n * 16 + (lane & 15);
                int byte = r * 128 + s * 64 + ((lane >> 4) << 4);
                byte ^= (r & 7) << 4;
                bfr[n] = *(const bf16x8*)(sB + byte);
            }
            #pragma unroll
            for (int m = 0; m < 4; ++m)
                #pragma unroll
                for (int n = 0; n < 4; ++n)
                    acc[m][n] = __builtin_amdgcn_mfma_f32_16x16x32_bf16(
                        af[m], bfr[n], acc[m][n], 0, 0, 0);
        }
        cur ^= 1;
    }
    #undef STAGE_NN

    unsigned short* st = (unsigned short*)sm;
    __syncthreads();
    #pragma unroll
    for (int m = 0; m < 4; ++m)
        #pragma unroll
        for (int n = 0; n < 4; ++n)
            #pragma unroll
            for (int r4 = 0; r4 < 4; ++r4) {
                int jl = wm * 64 + m * 16 + ((lane >> 4) << 2) + r4;
                int nl = wn * 64 + n * 16 + (lane & 15);
                st[jl * 136 + nl] = f2bf(acc[m][n][r4]);
            }
    __syncthreads();
    #pragma unroll
    for (int it = 0; it < 8; ++it) {
        int idx = t + it * 256, jl = idx >> 4, l16 = idx & 15;
        int4 pv = *(int4*)((char*)sm + jl * 272 + l16 * 16);
        *(int4*)(Cg + (size_t)b * cBatch + (size_t)(j0 + jl) * DIMC + n0 + l16 * 8) = pv;
    }
}

// ---------------------------------------------------------------------------
// K4: fused rsq + S + softmax per (b,h); R12: emits attnT bf16 [b][h][d][c]
// (transposed, coalesced) for the MFMA-based wp2 kernel.
// ---------------------------------------------------------------------------
__global__ __launch_bounds__(256) void s_softmax(
    const unsigned short* __restrict__ TU, const unsigned short* __restrict__ Wb,
    unsigned short* __restrict__ attnT)
{
    const int bh = blockIdx.x;
    const int b = bh >> 3, h = bh & 7;
    const unsigned short* A = TU + ((size_t)b * 1024 + h * 64) * DIMC;   // T rows
    const unsigned short* B = Wb + 262144 + (size_t)(h * 64) * DIMC;     // Wk rows

    __shared__ __align__(16) char sm[32768];
    __shared__ float sS[64][65];
    __shared__ float srq[64];
    __shared__ float srk[64];
    __shared__ unsigned short aT[64][65];

    const int t = threadIdx.x, lane = t & 63, w = t >> 6;
    const int wm = w >> 1, wn = w & 1;
    const int rsub = lane >> 3;
    const int srccol = ((lane & 7) ^ rsub) << 3;

    // fused row-dots for rsq_q / rsq_k
    {
        const int rid  = t >> 1;
        const int half = t & 1;
        const int isK  = (rid >= 64);
        const int rl   = rid & 63;
        const unsigned short* ar = TU + ((size_t)b * 1024 + (isK ? 512 : 0) + h * 64 + rl) * DIMC
                                 + half * 256;
        const unsigned short* wr = Wb + (isK ? 262144 : 0) + (size_t)(h * 64 + rl) * DIMC
                                 + half * 256;
        float s = 0.f;
        #pragma unroll 8
        for (int i = 0; i < 32; ++i) {
            Pack8 pa, pw;
            pa.v = *(const int4*)(ar + i * 8);
            pw.v = *(const int4*)(wr + i * 8);
            #pragma unroll
            for (int e = 0; e < 8; ++e) s = fmaf(bf2f(pa.u[e]), bf2f(pw.u[e]), s);
        }
        s += __shfl_xor(s, 1, 2);
        if (half == 0) {
            float r = 1.0f / fmaxf(sqrtf(s), EPSN);
            if (isK) srk[rl] = r; else srq[rl] = r;
        }
    }

    f32x4 zero = {0.f, 0.f, 0.f, 0.f};
    f32x4 acc[2][2];
    #pragma unroll
    for (int m = 0; m < 2; ++m)
        #pragma unroll
        for (int n = 0; n < 2; ++n) acc[m][n] = zero;

    #define STAGE_S(buf, c0)                                                    \
        {                                                                       \
            char* dst = sm + (buf) * 16384;                                     \
            _Pragma("unroll")                                                   \
            for (int i = 0; i < 2; ++i) {                                       \
                int ii = w * 2 + i;                                             \
                gload_lds16(A + (size_t)(ii * 8 + rsub) * DIMC + (c0) + srccol, \
                            dst + ii * 1024);                                   \
                gload_lds16(B + (size_t)(ii * 8 + rsub) * DIMC + (c0) + srccol, \
                            dst + 8192 + ii * 1024);                            \
            }                                                                   \
        }

    STAGE_S(0, 0);
    int cur = 0;
    for (int c0 = 0; c0 < DIMC; c0 += 64) {
        __syncthreads();
        if (c0 + 64 < DIMC) STAGE_S(cur ^ 1, c0 + 64);
        const char* sA = sm + cur * 16384;
        const char* sB = sA + 8192;
        #pragma unroll
        for (int s = 0; s < 2; ++s) {
            bf16x8 aq[2], bk[2];
            #pragma unroll
            for (int m = 0; m < 2; ++m) {
                int r = wm * 32 + m * 16 + (lane & 15);
                int byte = r * 128 + s * 64 + ((lane >> 4) << 4);
                byte ^= (r & 7) << 4;
                aq[m] = *(const bf16x8*)(sA + byte);
            }
            #pragma unroll
            for (int n = 0; n < 2; ++n) {
                int r = wn * 32 + n * 16 + (lane & 15);
                int byte = r * 128 + s * 64 + ((lane >> 4) << 4);
                byte ^= (r & 7) << 4;
                bk[n] = *(const bf16x8*)(sB + byte);
            }
            #pragma unroll
            for (int m = 0; m < 2; ++m)
                #pragma unroll
                for (int n = 0; n < 2; ++n)
                    acc[m][n] = __builtin_amdgcn_mfma_f32_16x16x32_bf16(
                        aq[m], bk[n], acc[m][n], 0, 0, 0);
        }
        cur ^= 1;
    }
    #undef STAGE_S

    #pragma unroll
    for (int m = 0; m < 2; ++m)
        #pragma unroll
        for (int n = 0; n < 2; ++n)
            #pragma unroll
            for (int r4 = 0; r4 < 4; ++r4) {
                int r = wm * 32 + m * 16 + ((lane >> 4) << 2) + r4;
                int c = wn * 32 + n * 16 + (lane & 15);
                sS[r][c] = acc[m][n][r4];
            }
    __syncthreads();

    const int r = t >> 2;       // attn row (c-index of attnT)
    const int p = t & 3;
    const float rq = srq[r];
    float row[16];
    #pragma unroll
    for (int c = 0; c < 16; ++c)
        row[c] = sS[r][p * 16 + c] * SCALE * rq * srk[p * 16 + c];
    float mx = row[0];
    #pragma unroll
    for (int c = 1; c < 16; ++c) mx = fmaxf(mx, row[c]);
    mx = fmaxf(mx, __shfl_xor(mx, 1, 4));
    mx = fmaxf(mx, __shfl_xor(mx, 2, 4));
    float sum = 0.f;
    #pragma unroll
    for (int c = 0; c < 16; ++c) { row[c] = __expf(row[c] - mx); sum += row[c]; }
    sum += __shfl_xor(sum, 1, 4);
    sum += __shfl_xor(sum, 2, 4);
    const float inv = 1.0f / sum;
    // write transposed into LDS: aT[d][c] = attn[c=r][d]
    #pragma unroll
    for (int i = 0; i < 16; ++i)
        aT[p * 16 + i][r] = f2bf(row[i] * inv);
    __syncthreads();
    // coalesced store: attnT[b][h][d][c]
    {
        const int d  = t >> 2;
        const int ch = t & 3;
        Pack8 o0, o1;
        #pragma unroll
        for (int e = 0; e < 8; ++e) { o0.u[e] = aT[d][ch * 16 + e]; o1.u[e] = aT[d][ch * 16 + 8 + e]; }
        unsigned short* dst = attnT + (((size_t)bh * 64) + d) * 64 + ch * 16;
        *(int4*)(dst)     = o0.v;
        *(int4*)(dst + 8) = o1.v;
    }
}

// ---------------------------------------------------------------------------
// K5 (R12): Wp2 via MFMA. Wp2[b][j][h*64+d] = sum_c Wpb[j][h*64+c]*attnT[bh][d][c]
// grid (jt=4 x128, h=8, b=8). Single K-tile (K=64), A 128x64, B 64x64.
// ---------------------------------------------------------------------------
__global__ __launch_bounds__(256) void wp2_mfma(
    const unsigned short* __restrict__ Wpb, const unsigned short* __restrict__ attnT,
    unsigned short* __restrict__ Wp2b)
{
    const int j0 = blockIdx.x * 128;
    const int h  = blockIdx.y;
    const int b  = blockIdx.z;
    const unsigned short* A = Wpb + (size_t)j0 * DIMC + h * 64;          // rows j, stride 512
    const unsigned short* B = attnT + (size_t)(b * 8 + h) * 4096;        // rows d, stride 64

    __shared__ __align__(16) char sm[24576];   // A 16KB @0, B 8KB @16384

    const int t = threadIdx.x, lane = t & 63, w = t >> 6;
    const int rsub = lane >> 3;
    const int srccol = ((lane & 7) ^ rsub) << 3;

    #pragma unroll
    for (int i = 0; i < 4; ++i) {
        int ii = w * 4 + i;    // 0..15 -> 128 A rows
        gload_lds16(A + (size_t)(ii * 8 + rsub) * DIMC + srccol, sm + ii * 1024);
    }
    #pragma unroll
    for (int i = 0; i < 2; ++i) {
        int ii = w * 2 + i;    // 0..7 -> 64 B rows
        gload_lds16(B + (size_t)(ii * 8 + rsub) * 64 + srccol, sm + 16384 + ii * 1024);
    }
    __syncthreads();

    f32x4 zero = {0.f, 0.f, 0.f, 0.f};
    f32x4 acc[2][4];
    #pragma unroll
    for (int m = 0; m < 2; ++m)
        #pragma unroll
        for (int n = 0; n < 4; ++n) acc[m][n] = zero;

    #pragma unroll
    for (int s = 0; s < 2; ++s) {
        bf16x8 af[2], bfr[4];
        #pragma unroll
        for (int m = 0; m < 2; ++m) {
            int r = w * 32 + m * 16 + (lane & 15);
            int byte = r * 128 + s * 64 + ((lane >> 4) << 4);
            byte ^= (r & 7) << 4;
            af[m] = *(const bf16x8*)(sm + byte);
        }
        #pragma unroll
        for (int n = 0; n < 4; ++n) {
            int r = n * 16 + (lane & 15);
            int byte = r * 128 + s * 64 + ((lane >> 4) << 4);
            byte ^= (r & 7) << 4;
            bfr[n] = *(const bf16x8*)(sm + 16384 + byte);
        }
        #pragma unroll
        for (int m = 0; m < 2; ++m)
            #pragma unroll
            for (int n = 0; n < 4; ++n)
                acc[m][n] = __builtin_amdgcn_mfma_f32_16x16x32_bf16(
                    af[m], bfr[n], acc[m][n], 0, 0, 0);
    }

    // stage [128j][64d] bf16, stride 72, then coalesced stores
    unsigned short* st = (unsigned short*)sm;
    __syncthreads();
    #pragma unroll
    for (int m = 0; m < 2; ++m)
        #pragma unroll
        for (int n = 0; n < 4; ++n)
            #pragma unroll
            for (int r4 = 0; r4 < 4; ++r4) {
                int jl = w * 32 + m * 16 + ((lane >> 4) << 2) + r4;
                int dl = n * 16 + (lane & 15);
                st[jl * 72 + dl] = f2bf(acc[m][n][r4]);
            }
    __syncthreads();
    #pragma unroll
    for (int it = 0; it < 4; ++it) {
        int idx = t + it * 256, jl = idx >> 3, ch = idx & 7;
        int4 pv = *(int4*)((char*)sm + jl * 144 + ch * 16);
        *(int4*)(Wp2b + ((size_t)b * DIMC + j0 + jl) * DIMC + h * 64 + ch * 8) = pv;
    }
}

// ---------------------------------------------------------------------------
// K6: final GEMM: out[b][j][n] = sum_c3 Wfb[b][j][c3] * xT[b][n][c3]
// ---------------------------------------------------------------------------
__global__ __launch_bounds__(256) void final_mfma(
    const unsigned short* __restrict__ Wfb, const unsigned short* __restrict__ xT,
    float* __restrict__ out)
{
    const int b  = blockIdx.z;
    const int j0 = blockIdx.y * 128;
    const int n0 = blockIdx.x * 128;
    const unsigned short* A = Wfb + (size_t)b * DIMC * DIMC + (size_t)j0 * DIMC;
    const unsigned short* B = xT + (size_t)b * HW * DIMC + (size_t)n0 * DIMC;

    __shared__ __align__(16) char sm[65536];

    const int t = threadIdx.x, lane = t & 63, w = t >> 6;
    const int wm = w >> 1, wn = w & 1;
    const int rsub = lane >> 3;
    const int srccol = ((lane & 7) ^ rsub) << 3;

    f32x4 zero = {0.f, 0.f, 0.f, 0.f};
    f32x4 acc[4][4];
    #pragma unroll
    for (int m = 0; m < 4; ++m)
        #pragma unroll
        for (int n = 0; n < 4; ++n) acc[m][n] = zero;

    #define STAGE_FIN(buf, c0)                                                  \
        {                                                                       \
            char* dst = sm + (buf) * 32768;                                     \
            _Pragma("unroll")                                                   \
            for (int i = 0; i < 4; ++i) {                                       \
                int ii = w * 4 + i;                                             \
                gload_lds16(A + (size_t)(ii * 8 + rsub) * DIMC + (c0) + srccol, \
                            dst + ii * 1024);                                   \
                gload_lds16(B + (size_t)(ii * 8 + rsub) * DIMC + (c0) + srccol, \
                            dst + 16384 + ii * 1024);                           \
            }                                                                   \
        }

    STAGE_FIN(0, 0);
    int cur = 0;
    for (int c0 = 0; c0 < DIMC; c0 += 64) {
        __syncthreads();
        if (c0 + 64 < DIMC) STAGE_FIN(cur ^ 1, c0 + 64);
        const char* sA = sm + cur * 32768;
        const char* sB = sA + 16384;
        #pragma unroll
        for (int s = 0; s < 2; ++s) {
            bf16x8 af[4], bfr[4];
            #pragma unroll
            for (int m = 0; m < 4; ++m) {
                int r = wm * 64 + m * 16 + (lane & 15);
                int byte = r * 128 + s * 64 + ((lane >> 4) << 4);
                byte ^= (r & 7) << 4;
                af[m] = *(const bf16x8*)(sA + byte);
            }
            #pragma unroll
            for (int n = 0; n < 4; ++n) {
                int r = wn * 64 + n * 16 + (lane & 15);
                int byte = r * 128 + s * 64 + ((lane >> 4) << 4);
                byte ^= (r & 7) << 4;
                bfr[n] = *(const bf16x8*)(sB + byte);
            }
            #pragma unroll
            for (int m = 0; m < 4; ++m)
                #pragma unroll
                for (int n = 0; n < 4; ++n)
                    acc[m][n] = __builtin_amdgcn_mfma_f32_16x16x32_bf16(
                        af[m], bfr[n], acc[m][n], 0, 0, 0);
        }
        cur ^= 1;
    }
    #undef STAGE_FIN

    #pragma unroll
    for (int m = 0; m < 4; ++m)
        #pragma unroll
        for (int r4 = 0; r4 < 4; ++r4) {
            int j = j0 + wm * 64 + m * 16 + ((lane >> 4) << 2) + r4;
            size_t rowbase = ((size_t)b * DIMC + j) * HW + n0 + wn * 64 + (lane & 15);
            #pragma unroll
            for (int n = 0; n < 4; ++n)
                out[rowbase + n * 16] = acc[m][n][r4];
        }
}

// ---------------------------------------------------------------------------
// Workspace (bytes):
//   xT    @ 0           67,108,864
//   xmb   @ 67108864    67,108,864
//   Wb    @ 134217728    1,048,576
//   WvT   @ 135266304      524,288
//   Wpb   @ 135790592      524,288
//   G     @ 136314880    4,194,304
//   TU    @ 140509184    8,388,608
//   attnT @ 148897792      524,288
//   Wp2b  @ 149422080    4,194,304
//   Wfb   @ 153616384    4,194,304
//   Gpart @ 157810688   10,485,760   [32 grp][10 tiles][128][128] bf16
//   end ~168.3 MB
// ---------------------------------------------------------------------------
extern "C" void kernel_launch(void* const* d_in, const int* in_sizes, int n_in,
                              void* d_out, int out_size, void* d_ws, size_t ws_size,
                              hipStream_t stream)
{
    const float* x    = (const float*)d_in[0];
    const float* mask = (const float*)d_in[1];
    const float* Wq   = (const float*)d_in[2];
    const float* Wk   = (const float*)d_in[3];
    const float* Wv   = (const float*)d_in[4];
    const float* Wp   = (const float*)d_in[5];
    float* out = (float*)d_out;
    char* wsb = (char*)d_ws;

    unsigned short* xT   = (unsigned short*)(wsb + 0);
    unsigned short* xmb  = (unsigned short*)(wsb + 67108864);
    unsigned short* Wb   = (unsigned short*)(wsb + 134217728);
    unsigned short* WvT  = (unsigned short*)(wsb + 135266304);
    unsigned short* Wpb  = (unsigned short*)(wsb + 135790592);
    unsigned short* G    = (unsigned short*)(wsb + 136314880);
    unsigned short* TU   = (unsigned short*)(wsb + 140509184);
    unsigned short* attnT= (unsigned short*)(wsb + 148897792);
    unsigned short* Wp2b = (unsigned short*)(wsb + 149422080);
    unsigned short* Wfb  = (unsigned short*)(wsb + 153616384);
    unsigned short* Gpart= (unsigned short*)(wsb + 157810688);

    prep_wx        <<<4928,            256, 0, stream>>>(Wq, Wk, Wv, Wp, x, mask,
                                                         Wb, WvT, Wpb, xT, xmb);
    gram_mfma      <<<dim3(10, 32),    256, 0, stream>>>(xmb, Gpart);
    gram_reduce_sym<<<dim3(10, 8),     256, 0, stream>>>(Gpart, G);
    gemm_nn_128    <<<dim3(4, 8, 8),   256, 0, stream>>>(Wb, (size_t)0, G, (size_t)(DIMC*DIMC), TU, (size_t)(1024*DIMC));
    s_softmax      <<<64,              256, 0, stream>>>(TU, Wb, attnT);
    wp2_mfma       <<<dim3(4, 8, 8),   256, 0, stream>>>(Wpb, attnT, Wp2b);
    gemm_nn_128    <<<dim3(4, 4, 8),   256, 0, stream>>>(Wp2b, (size_t)(DIMC*DIMC), WvT, (size_t)0, Wfb, (size_t)(DIMC*DIMC));
    final_mfma     <<<dim3(32, 4, 8),  256, 0, stream>>>(Wfb, xT, out);
}

// Round 13
// 111.949 us; speedup vs baseline: 1.1975x; 1.0259x over previous
//
#include <hip/hip_runtime.h>
#include <math.h>

#define DIMC 512
#define HW 4096
#define SCALE 0.125f
#define EPSN 1e-12f

typedef __attribute__((ext_vector_type(8))) short bf16x8;
typedef __attribute__((ext_vector_type(4))) float f32x4;

__device__ __forceinline__ unsigned short f2bf(float f) {
    union { float f; unsigned int u; } v; v.f = f;
    unsigned int u = v.u;
    return (unsigned short)((u + 0x7fffu + ((u >> 16) & 1u)) >> 16);
}
__device__ __forceinline__ float bf2f(unsigned short h) {
    union { unsigned int u; float f; } v; v.u = ((unsigned int)h) << 16;
    return v.f;
}

union Pack8 { int4 v; unsigned short u[8]; };

__device__ __forceinline__ void gload_lds16(const unsigned short* src, char* ldst) {
    __builtin_amdgcn_global_load_lds(
        (const __attribute__((address_space(1))) void*)src,
        (__attribute__((address_space(3))) void*)ldst, 16, 0, 0);
}

// ---------------------------------------------------------------------------
// P1 (all prep merged): blocks 0..511   : Wq,Wk -> Wb bf16
//                       blocks 512..575 : WvT = bf16(Wv^T)
//                       blocks 576..831 : Wp -> Wpb bf16
//                       blocks 832..4927: prep_x (xT + xmb)
// ---------------------------------------------------------------------------
__global__ __launch_bounds__(256) void prep_wx(
    const float* __restrict__ Wq, const float* __restrict__ Wk,
    const float* __restrict__ Wv, const float* __restrict__ Wp,
    const float* __restrict__ x, const float* __restrict__ mask,
    unsigned short* __restrict__ Wb, unsigned short* __restrict__ WvT,
    unsigned short* __restrict__ Wpb,
    unsigned short* __restrict__ xT, unsigned short* __restrict__ xmb)
{
    const int blk = blockIdx.x;
    const int t = threadIdx.x;
    if (blk < 512) {
        int i = (blk * 256 + t) * 4;
        const float* s = (i < 262144) ? Wq : Wk;
        int off = i & 262143;
        float4 v4 = *(const float4*)(s + off);
        ushort4 o;
        o.x = f2bf(v4.x); o.y = f2bf(v4.y); o.z = f2bf(v4.z); o.w = f2bf(v4.w);
        *(ushort4*)(Wb + i) = o;
    } else if (blk < 576) {
        const int bb = blk - 512;
        const int cp0 = (bb >> 3) * 64;
        const int c30 = (bb & 7) * 64;
        __shared__ unsigned short sT[64][65];
        #pragma unroll
        for (int i = 0; i < 4; ++i) {
            int ch = t + i * 256;
            int r = ch >> 4, col4 = (ch & 15) * 4;
            float4 v4 = *(const float4*)(Wv + (size_t)(cp0 + r) * DIMC + c30 + col4);
            sT[r][col4 + 0] = f2bf(v4.x); sT[r][col4 + 1] = f2bf(v4.y);
            sT[r][col4 + 2] = f2bf(v4.z); sT[r][col4 + 3] = f2bf(v4.w);
        }
        __syncthreads();
        #pragma unroll
        for (int i = 0; i < 2; ++i) {
            int ch = t + i * 256;
            int n = ch >> 3, cc = (ch & 7) * 8;
            Pack8 pk;
            #pragma unroll
            for (int e = 0; e < 8; ++e) pk.u[e] = sT[cc + e][n];
            *(int4*)(WvT + (size_t)(c30 + n) * DIMC + cp0 + cc) = pk.v;
        }
    } else if (blk < 832) {
        int i = ((blk - 576) * 256 + t) * 4;
        float4 v4 = *(const float4*)(Wp + i);
        ushort4 o;
        o.x = f2bf(v4.x); o.y = f2bf(v4.y); o.z = f2bf(v4.z); o.w = f2bf(v4.w);
        *(ushort4*)(Wpb + i) = o;
    } else {
        const int idx = blk - 832;
        const int n0 = (idx & 63) * 64;
        const int c0 = ((idx >> 6) & 7) * 64;
        const int b  = idx >> 9;
        __shared__ unsigned short sT[64][65];
        #pragma unroll
        for (int i = 0; i < 4; ++i) {
            int ch = t + i * 256;
            int r = ch >> 4, col4 = (ch & 15) * 4;
            float4 v4 = *(const float4*)(x + ((size_t)b * DIMC + c0 + r) * HW + n0 + col4);
            sT[r][col4 + 0] = f2bf(v4.x); sT[r][col4 + 1] = f2bf(v4.y);
            sT[r][col4 + 2] = f2bf(v4.z); sT[r][col4 + 3] = f2bf(v4.w);
            float4 mv = *(const float4*)(mask + (size_t)b * HW + n0 + col4);
            ushort4 xm;
            xm.x = f2bf(v4.x * mv.x); xm.y = f2bf(v4.y * mv.y);
            xm.z = f2bf(v4.z * mv.z); xm.w = f2bf(v4.w * mv.w);
            *(ushort4*)(xmb + ((size_t)b * DIMC + c0 + r) * HW + n0 + col4) = xm;
        }
        __syncthreads();
        #pragma unroll
        for (int i = 0; i < 2; ++i) {
            int ch = t + i * 256;
            int n = ch >> 3, cc = (ch & 7) * 8;
            Pack8 pk;
            #pragma unroll
            for (int e = 0; e < 8; ++e) pk.u[e] = sT[cc + e][n];
            *(int4*)(xT + ((size_t)b * HW + n0 + n) * DIMC + c0 + cc) = pk.v;
        }
    }
}

// ---------------------------------------------------------------------------
// K1: TRIANGULAR Gram GEMM, split-K, XCD-grouped (R13):
// 1D grid 320; r=f&7 (XCD), q=f>>3; pair=q>>2, grp=r+((q&3)<<3) -> all 10
// pair-blocks of a (b,sp) group land on one XCD, temporally adjacent, so the
// group's 4 xmb panels (1 MB) stay in that XCD's L2 (fixes 5x panel re-fetch).
// ---------------------------------------------------------------------------
__global__ __launch_bounds__(256) void gram_mfma(
    const unsigned short* __restrict__ xmb, unsigned short* __restrict__ Gpart)
{
    const int f = blockIdx.x;            // 0..319
    const int r8 = f & 7, q = f >> 3;
    const int pair = q >> 2;             // 0..9
    const int grp  = r8 + ((q & 3) << 3);// 0..31
    const int b  = grp & 7;
    const int sp = grp >> 3;
    const int TA[10] = {0,0,0,0,1,1,1,2,2,3};
    const int TB[10] = {0,1,2,3,1,2,3,2,3,3};
    const int cA0 = TA[pair] * 128;
    const int cB0 = TB[pair] * 128;
    const unsigned short* A = xmb + (size_t)b * DIMC * HW + (size_t)cA0 * HW + sp * 1024;
    const unsigned short* B = xmb + (size_t)b * DIMC * HW + (size_t)cB0 * HW + sp * 1024;

    __shared__ __align__(16) char sm[65536];

    const int t = threadIdx.x, lane = t & 63, w = t >> 6;
    const int wm = w >> 1, wn = w & 1;
    const int rsub = lane >> 3;
    const int srccol = ((lane & 7) ^ rsub) << 3;

    f32x4 zero = {0.f, 0.f, 0.f, 0.f};
    f32x4 acc[4][4];
    #pragma unroll
    for (int m = 0; m < 4; ++m)
        #pragma unroll
        for (int n = 0; n < 4; ++n) acc[m][n] = zero;

    #define STAGE_G(buf, c0)                                                  \
        {                                                                     \
            char* dst = sm + (buf) * 32768;                                   \
            _Pragma("unroll")                                                 \
            for (int i = 0; i < 4; ++i) {                                     \
                int ii = w * 4 + i;                                           \
                gload_lds16(A + (size_t)(ii * 8 + rsub) * HW + (c0) + srccol, \
                            dst + ii * 1024);                                 \
                gload_lds16(B + (size_t)(ii * 8 + rsub) * HW + (c0) + srccol, \
                            dst + 16384 + ii * 1024);                         \
            }                                                                 \
        }

    STAGE_G(0, 0);
    int cur = 0;
    for (int c0 = 0; c0 < 1024; c0 += 64) {
        __syncthreads();
        if (c0 + 64 < 1024) STAGE_G(cur ^ 1, c0 + 64);
        const char* sA = sm + cur * 32768;
        const char* sB = sA + 16384;
        #pragma unroll
        for (int s = 0; s < 2; ++s) {
            bf16x8 af[4], bfr[4];
            #pragma unroll
            for (int m = 0; m < 4; ++m) {
                int r = wm * 64 + m * 16 + (lane & 15);
                int byte = r * 128 + s * 64 + ((lane >> 4) << 4);
                byte ^= (r & 7) << 4;
                af[m] = *(const bf16x8*)(sA + byte);
            }
            #pragma unroll
            for (int n = 0; n < 4; ++n) {
                int r = wn * 64 + n * 16 + (lane & 15);
                int byte = r * 128 + s * 64 + ((lane >> 4) << 4);
                byte ^= (r & 7) << 4;
                bfr[n] = *(const bf16x8*)(sB + byte);
            }
            #pragma unroll
            for (int m = 0; m < 4; ++m)
                #pragma unroll
                for (int n = 0; n < 4; ++n)
                    acc[m][n] = __builtin_amdgcn_mfma_f32_16x16x32_bf16(
                        af[m], bfr[n], acc[m][n], 0, 0, 0);
        }
        cur ^= 1;
    }
    #undef STAGE_G

    unsigned short* st = (unsigned short*)sm;
    __syncthreads();
    #pragma unroll
    for (int m = 0; m < 4; ++m)
        #pragma unroll
        for (int n = 0; n < 4; ++n)
            #pragma unroll
            for (int r4 = 0; r4 < 4; ++r4) {
                int jl = wm * 64 + m * 16 + ((lane >> 4) << 2) + r4;
                int nl = wn * 64 + n * 16 + (lane & 15);
                st[jl * 136 + nl] = f2bf(acc[m][n][r4]);
            }
    __syncthreads();
    unsigned short* Gp = Gpart + ((size_t)(sp * 8 + b) * 10 + pair) * 16384;
    #pragma unroll
    for (int it = 0; it < 8; ++it) {
        int idx = t + it * 256, jl = idx >> 4, l16 = idx & 15;
        int4 pv = *(int4*)((char*)sm + jl * 272 + l16 * 16);
        *(int4*)(Gp + (size_t)jl * 128 + l16 * 8) = pv;
    }
}

// ---------------------------------------------------------------------------
// K1b: reduce 4 split partials of each (pair,b) tile -> G[512][512] bf16,
// writing BOTH the tile and its transposed mirror (G symmetric).
// ---------------------------------------------------------------------------
__global__ __launch_bounds__(256) void gram_reduce_sym(
    const unsigned short* __restrict__ Gpart, unsigned short* __restrict__ G)
{
    const int pair = blockIdx.x;
    const int b    = blockIdx.y;
    const int TA[10] = {0,0,0,0,1,1,1,2,2,3};
    const int TB[10] = {0,1,2,3,1,2,3,2,3,3};
    const int ta = TA[pair], tb = TB[pair];
    const int t = threadIdx.x;

    __shared__ unsigned short sT[128][130];
    unsigned short* Gb = G + (size_t)b * DIMC * DIMC;

    #pragma unroll
    for (int ch = 0; ch < 8; ++ch) {
        int e = ch * 2048 + t * 8;
        int i = e >> 7, j = e & 127;
        Pack8 p0, p1, p2, p3, o;
        p0.v = *(const int4*)(Gpart + ((size_t)(0 * 8 + b) * 10 + pair) * 16384 + e);
        p1.v = *(const int4*)(Gpart + ((size_t)(1 * 8 + b) * 10 + pair) * 16384 + e);
        p2.v = *(const int4*)(Gpart + ((size_t)(2 * 8 + b) * 10 + pair) * 16384 + e);
        p3.v = *(const int4*)(Gpart + ((size_t)(3 * 8 + b) * 10 + pair) * 16384 + e);
        #pragma unroll
        for (int k = 0; k < 8; ++k) {
            unsigned short s = f2bf(bf2f(p0.u[k]) + bf2f(p1.u[k]) + bf2f(p2.u[k]) + bf2f(p3.u[k]));
            o.u[k] = s;
            sT[i][j + k] = s;
        }
        *(int4*)(Gb + (size_t)(ta * 128 + i) * DIMC + tb * 128 + j) = o.v;
    }
    if (ta != tb) {
        __syncthreads();
        #pragma unroll
        for (int ch = 0; ch < 8; ++ch) {
            int e = ch * 2048 + t * 8;
            int i2 = e >> 7, j2 = e & 127;
            Pack8 o;
            #pragma unroll
            for (int k = 0; k < 8; ++k) o.u[k] = sT[j2 + k][i2];
            *(int4*)(Gb + (size_t)(tb * 128 + i2) * DIMC + ta * 128 + j2) = o.v;
        }
    }
}

// ---------------------------------------------------------------------------
// K2: generic 128x128 NT GEMM, K=512, row stride 512, bf16 out.
// ---------------------------------------------------------------------------
__global__ __launch_bounds__(256) void gemm_nn_128(
    const unsigned short* __restrict__ Ag, size_t aBatch,
    const unsigned short* __restrict__ Bg, size_t bBatch,
    unsigned short* __restrict__ Cg, size_t cBatch)
{
    const int b  = blockIdx.z;
    const int j0 = blockIdx.y * 128;
    const int n0 = blockIdx.x * 128;
    const unsigned short* A = Ag + (size_t)b * aBatch + (size_t)j0 * DIMC;
    const unsigned short* B = Bg + (size_t)b * bBatch + (size_t)n0 * DIMC;

    __shared__ __align__(16) char sm[65536];

    const int t = threadIdx.x, lane = t & 63, w = t >> 6;
    const int wm = w >> 1, wn = w & 1;
    const int rsub = lane >> 3;
    const int srccol = ((lane & 7) ^ rsub) << 3;

    f32x4 zero = {0.f, 0.f, 0.f, 0.f};
    f32x4 acc[4][4];
    #pragma unroll
    for (int m = 0; m < 4; ++m)
        #pragma unroll
        for (int n = 0; n < 4; ++n) acc[m][n] = zero;

    #define STAGE_NN(buf, c0)                                                   \
        {                                                                       \
            char* dst = sm + (buf) * 32768;                                     \
            _Pragma("unroll")                                                   \
            for (int i = 0; i < 4; ++i) {                                       \
                int ii = w * 4 + i;                                             \
                gload_lds16(A + (size_t)(ii * 8 + rsub) * DIMC + (c0) + srccol, \
                            dst + ii * 1024);                                   \
                gload_lds16(B + (size_t)(ii * 8 + rsub) * DIMC + (c0) + srccol, \
                            dst + 16384 + ii * 1024);                           \
            }                                                                   \
        }

    STAGE_NN(0, 0);
    int cur = 0;
    for (int c0 = 0; c0 < DIMC; c0 += 64) {
        __syncthreads();
        if (c0 + 64 < DIMC) STAGE_NN(cur ^ 1, c0 + 64);
        const char* sA = sm + cur * 32768;
        const char* sB = sA + 16384;
        #pragma unroll
        for (int s = 0; s < 2; ++s) {
            bf16x8 af[4], bfr[4];
            #pragma unroll
            for (int m = 0; m < 4; ++m) {
                int r = wm * 64 + m * 16 + (lane & 15);
                int byte = r * 128 + s * 64 + ((lane >> 4) << 4);
                byte ^= (r & 7) << 4;
                af[m] = *(const bf16x8*)(sA + byte);
            }
            #pragma unroll
            for (int n = 0; n < 4; ++n) {
                int r = wn * 64 + n * 16 + (lane & 15);
                int byte = r * 128 + s * 64 + ((lane >> 4) << 4);
                byte ^= (r & 7) << 4;
                bfr[n] = *(const bf16x8*)(sB + byte);
            }
            #pragma unroll
            for (int m = 0; m < 4; ++m)
                #pragma unroll
                for (int n = 0; n < 4; ++n)
                    acc[m][n] = __builtin_amdgcn_mfma_f32_16x16x32_bf16(
                        af[m], bfr[n], acc[m][n], 0, 0, 0);
        }
        cur ^= 1;
    }
    #undef STAGE_NN

    unsigned short* st = (unsigned short*)sm;
    __syncthreads();
    #pragma unroll
    for (int m = 0; m < 4; ++m)
        #pragma unroll
        for (int n = 0; n < 4; ++n)
            #pragma unroll
            for (int r4 = 0; r4 < 4; ++r4) {
                int jl = wm * 64 + m * 16 + ((lane >> 4) << 2) + r4;
                int nl = wn * 64 + n * 16 + (lane & 15);
                st[jl * 136 + nl] = f2bf(acc[m][n][r4]);
            }
    __syncthreads();
    #pragma unroll
    for (int it = 0; it < 8; ++it) {
        int idx = t + it * 256, jl = idx >> 4, l16 = idx & 15;
        int4 pv = *(int4*)((char*)sm + jl * 272 + l16 * 16);
        *(int4*)(Cg + (size_t)b * cBatch + (size_t)(j0 + jl) * DIMC + n0 + l16 * 8) = pv;
    }
}

// ---------------------------------------------------------------------------
// K4: fused rsq + S + softmax per (b,h); emits attnT bf16 [b][h][d][c].
// ---------------------------------------------------------------------------
__global__ __launch_bounds__(256) void s_softmax(
    const unsigned short* __restrict__ TU, const unsigned short* __restrict__ Wb,
    unsigned short* __restrict__ attnT)
{
    const int bh = blockIdx.x;
    const int b = bh >> 3, h = bh & 7;
    const unsigned short* A = TU + ((size_t)b * 1024 + h * 64) * DIMC;
    const unsigned short* B = Wb + 262144 + (size_t)(h * 64) * DIMC;

    __shared__ __align__(16) char sm[32768];
    __shared__ float sS[64][65];
    __shared__ float srq[64];
    __shared__ float srk[64];
    __shared__ unsigned short aT[64][65];

    const int t = threadIdx.x, lane = t & 63, w = t >> 6;
    const int wm = w >> 1, wn = w & 1;
    const int rsub = lane >> 3;
    const int srccol = ((lane & 7) ^ rsub) << 3;

    {
        const int rid  = t >> 1;
        const int half = t & 1;
        const int isK  = (rid >= 64);
        const int rl   = rid & 63;
        const unsigned short* ar = TU + ((size_t)b * 1024 + (isK ? 512 : 0) + h * 64 + rl) * DIMC
                                 + half * 256;
        const unsigned short* wr = Wb + (isK ? 262144 : 0) + (size_t)(h * 64 + rl) * DIMC
                                 + half * 256;
        float s = 0.f;
        #pragma unroll 8
        for (int i = 0; i < 32; ++i) {
            Pack8 pa, pw;
            pa.v = *(const int4*)(ar + i * 8);
            pw.v = *(const int4*)(wr + i * 8);
            #pragma unroll
            for (int e = 0; e < 8; ++e) s = fmaf(bf2f(pa.u[e]), bf2f(pw.u[e]), s);
        }
        s += __shfl_xor(s, 1, 2);
        if (half == 0) {
            float r = 1.0f / fmaxf(sqrtf(s), EPSN);
            if (isK) srk[rl] = r; else srq[rl] = r;
        }
    }

    f32x4 zero = {0.f, 0.f, 0.f, 0.f};
    f32x4 acc[2][2];
    #pragma unroll
    for (int m = 0; m < 2; ++m)
        #pragma unroll
        for (int n = 0; n < 2; ++n) acc[m][n] = zero;

    #define STAGE_S(buf, c0)                                                    \
        {                                                                       \
            char* dst = sm + (buf) * 16384;                                     \
            _Pragma("unroll")                                                   \
            for (int i = 0; i < 2; ++i) {                                       \
                int ii = w * 2 + i;                                             \
                gload_lds16(A + (size_t)(ii * 8 + rsub) * DIMC + (c0) + srccol, \
                            dst + ii * 1024);                                   \
                gload_lds16(B + (size_t)(ii * 8 + rsub) * DIMC + (c0) + srccol, \
                            dst + 8192 + ii * 1024);                            \
            }                                                                   \
        }

    STAGE_S(0, 0);
    int cur = 0;
    for (int c0 = 0; c0 < DIMC; c0 += 64) {
        __syncthreads();
        if (c0 + 64 < DIMC) STAGE_S(cur ^ 1, c0 + 64);
        const char* sA = sm + cur * 16384;
        const char* sB = sA + 8192;
        #pragma unroll
        for (int s = 0; s < 2; ++s) {
            bf16x8 aq[2], bk[2];
            #pragma unroll
            for (int m = 0; m < 2; ++m) {
                int r = wm * 32 + m * 16 + (lane & 15);
                int byte = r * 128 + s * 64 + ((lane >> 4) << 4);
                byte ^= (r & 7) << 4;
                aq[m] = *(const bf16x8*)(sA + byte);
            }
            #pragma unroll
            for (int n = 0; n < 2; ++n) {
                int r = wn * 32 + n * 16 + (lane & 15);
                int byte = r * 128 + s * 64 + ((lane >> 4) << 4);
                byte ^= (r & 7) << 4;
                bk[n] = *(const bf16x8*)(sB + byte);
            }
            #pragma unroll
            for (int m = 0; m < 2; ++m)
                #pragma unroll
                for (int n = 0; n < 2; ++n)
                    acc[m][n] = __builtin_amdgcn_mfma_f32_16x16x32_bf16(
                        aq[m], bk[n], acc[m][n], 0, 0, 0);
        }
        cur ^= 1;
    }
    #undef STAGE_S

    #pragma unroll
    for (int m = 0; m < 2; ++m)
        #pragma unroll
        for (int n = 0; n < 2; ++n)
            #pragma unroll
            for (int r4 = 0; r4 < 4; ++r4) {
                int r = wm * 32 + m * 16 + ((lane >> 4) << 2) + r4;
                int c = wn * 32 + n * 16 + (lane & 15);
                sS[r][c] = acc[m][n][r4];
            }
    __syncthreads();

    const int r = t >> 2;
    const int p = t & 3;
    const float rq = srq[r];
    float row[16];
    #pragma unroll
    for (int c = 0; c < 16; ++c)
        row[c] = sS[r][p * 16 + c] * SCALE * rq * srk[p * 16 + c];
    float mx = row[0];
    #pragma unroll
    for (int c = 1; c < 16; ++c) mx = fmaxf(mx, row[c]);
    mx = fmaxf(mx, __shfl_xor(mx, 1, 4));
    mx = fmaxf(mx, __shfl_xor(mx, 2, 4));
    float sum = 0.f;
    #pragma unroll
    for (int c = 0; c < 16; ++c) { row[c] = __expf(row[c] - mx); sum += row[c]; }
    sum += __shfl_xor(sum, 1, 4);
    sum += __shfl_xor(sum, 2, 4);
    const float inv = 1.0f / sum;
    #pragma unroll
    for (int i = 0; i < 16; ++i)
        aT[p * 16 + i][r] = f2bf(row[i] * inv);
    __syncthreads();
    {
        const int d  = t >> 2;
        const int ch = t & 3;
        Pack8 o0, o1;
        #pragma unroll
        for (int e = 0; e < 8; ++e) { o0.u[e] = aT[d][ch * 16 + e]; o1.u[e] = aT[d][ch * 16 + 8 + e]; }
        unsigned short* dst = attnT + (((size_t)bh * 64) + d) * 64 + ch * 16;
        *(int4*)(dst)     = o0.v;
        *(int4*)(dst + 8) = o1.v;
    }
}

// ---------------------------------------------------------------------------
// K5: Wp2 via MFMA. Wp2[b][j][h*64+d] = sum_c Wpb[j][h*64+c]*attnT[bh][d][c]
// ---------------------------------------------------------------------------
__global__ __launch_bounds__(256) void wp2_mfma(
    const unsigned short* __restrict__ Wpb, const unsigned short* __restrict__ attnT,
    unsigned short* __restrict__ Wp2b)
{
    const int j0 = blockIdx.x * 128;
    const int h  = blockIdx.y;
    const int b  = blockIdx.z;
    const unsigned short* A = Wpb + (size_t)j0 * DIMC + h * 64;
    const unsigned short* B = attnT + (size_t)(b * 8 + h) * 4096;

    __shared__ __align__(16) char sm[24576];

    const int t = threadIdx.x, lane = t & 63, w = t >> 6;
    const int rsub = lane >> 3;
    const int srccol = ((lane & 7) ^ rsub) << 3;

    #pragma unroll
    for (int i = 0; i < 4; ++i) {
        int ii = w * 4 + i;
        gload_lds16(A + (size_t)(ii * 8 + rsub) * DIMC + srccol, sm + ii * 1024);
    }
    #pragma unroll
    for (int i = 0; i < 2; ++i) {
        int ii = w * 2 + i;
        gload_lds16(B + (size_t)(ii * 8 + rsub) * 64 + srccol, sm + 16384 + ii * 1024);
    }
    __syncthreads();

    f32x4 zero = {0.f, 0.f, 0.f, 0.f};
    f32x4 acc[2][4];
    #pragma unroll
    for (int m = 0; m < 2; ++m)
        #pragma unroll
        for (int n = 0; n < 4; ++n) acc[m][n] = zero;

    #pragma unroll
    for (int s = 0; s < 2; ++s) {
        bf16x8 af[2], bfr[4];
        #pragma unroll
        for (int m = 0; m < 2; ++m) {
            int r = w * 32 + m * 16 + (lane & 15);
            int byte = r * 128 + s * 64 + ((lane >> 4) << 4);
            byte ^= (r & 7) << 4;
            af[m] = *(const bf16x8*)(sm + byte);
        }
        #pragma unroll
        for (int n = 0; n < 4; ++n) {
            int r = n * 16 + (lane & 15);
            int byte = r * 128 + s * 64 + ((lane >> 4) << 4);
            byte ^= (r & 7) << 4;
            bfr[n] = *(const bf16x8*)(sm + 16384 + byte);
        }
        #pragma unroll
        for (int m = 0; m < 2; ++m)
            #pragma unroll
            for (int n = 0; n < 4; ++n)
                acc[m][n] = __builtin_amdgcn_mfma_f32_16x16x32_bf16(
                    af[m], bfr[n], acc[m][n], 0, 0, 0);
    }

    unsigned short* st = (unsigned short*)sm;
    __syncthreads();
    #pragma unroll
    for (int m = 0; m < 2; ++m)
        #pragma unroll
        for (int n = 0; n < 4; ++n)
            #pragma unroll
            for (int r4 = 0; r4 < 4; ++r4) {
                int jl = w * 32 + m * 16 + ((lane >> 4) << 2) + r4;
                int dl = n * 16 + (lane & 15);
                st[jl * 72 + dl] = f2bf(acc[m][n][r4]);
            }
    __syncthreads();
    #pragma unroll
    for (int it = 0; it < 4; ++it) {
        int idx = t + it * 256, jl = idx >> 3, ch = idx & 7;
        int4 pv = *(int4*)((char*)sm + jl * 144 + ch * 16);
        *(int4*)(Wp2b + ((size_t)b * DIMC + j0 + jl) * DIMC + h * 64 + ch * 8) = pv;
    }
}

// ---------------------------------------------------------------------------
// K6: final GEMM, XCD-grouped (R13): out[b][j][n] = sum_c3 Wfb[j][c3]*xT[n][c3]
// 1D grid 1024; r=f&7 (XCD), q=f>>3: jt=q&3 (FASTEST -> 4 j-blocks of the
// same xT n-tile run back-to-back on one XCD -> xT fetched once from HBM),
// n=r+8*((q>>2)&3), b=q>>4.
// ---------------------------------------------------------------------------
__global__ __launch_bounds__(256) void final_mfma(
    const unsigned short* __restrict__ Wfb, const unsigned short* __restrict__ xT,
    float* __restrict__ out)
{
    const int f = blockIdx.x;            // 0..1023
    const int r8 = f & 7, q = f >> 3;
    const int jt = q & 3;
    const int nt = r8 + (((q >> 2) & 3) << 3);   // 0..31
    const int b  = q >> 4;                        // 0..7
    const int j0 = jt * 128;
    const int n0 = nt * 128;
    const unsigned short* A = Wfb + (size_t)b * DIMC * DIMC + (size_t)j0 * DIMC;
    const unsigned short* B = xT + (size_t)b * HW * DIMC + (size_t)n0 * DIMC;

    __shared__ __align__(16) char sm[65536];

    const int t = threadIdx.x, lane = t & 63, w = t >> 6;
    const int wm = w >> 1, wn = w & 1;
    const int rsub = lane >> 3;
    const int srccol = ((lane & 7) ^ rsub) << 3;

    f32x4 zero = {0.f, 0.f, 0.f, 0.f};
    f32x4 acc[4][4];
    #pragma unroll
    for (int m = 0; m < 4; ++m)
        #pragma unroll
        for (int n = 0; n < 4; ++n) acc[m][n] = zero;

    #define STAGE_FIN(buf, c0)                                                  \
        {                                                                       \
            char* dst = sm + (buf) * 32768;                                     \
            _Pragma("unroll")                                                   \
            for (int i = 0; i < 4; ++i) {                                       \
                int ii = w * 4 + i;                                             \
                gload_lds16(A + (size_t)(ii * 8 + rsub) * DIMC + (c0) + srccol, \
                            dst + ii * 1024);                                   \
                gload_lds16(B + (size_t)(ii * 8 + rsub) * DIMC + (c0) + srccol, \
                            dst + 16384 + ii * 1024);                           \
            }                                                                   \
        }

    STAGE_FIN(0, 0);
    int cur = 0;
    for (int c0 = 0; c0 < DIMC; c0 += 64) {
        __syncthreads();
        if (c0 + 64 < DIMC) STAGE_FIN(cur ^ 1, c0 + 64);
        const char* sA = sm + cur * 32768;
        const char* sB = sA + 16384;
        #pragma unroll
        for (int s = 0; s < 2; ++s) {
            bf16x8 af[4], bfr[4];
            #pragma unroll
            for (int m = 0; m < 4; ++m) {
                int r = wm * 64 + m * 16 + (lane & 15);
                int byte = r * 128 + s * 64 + ((lane >> 4) << 4);
                byte ^= (r & 7) << 4;
                af[m] = *(const bf16x8*)(sA + byte);
            }
            #pragma unroll
            for (int n = 0; n < 4; ++n) {
                int r = wn * 64 + n * 16 + (lane & 15);
                int byte = r * 128 + s * 64 + ((lane >> 4) << 4);
                byte ^= (r & 7) << 4;
                bfr[n] = *(const bf16x8*)(sB + byte);
            }
            #pragma unroll
            for (int m = 0; m < 4; ++m)
                #pragma unroll
                for (int n = 0; n < 4; ++n)
                    acc[m][n] = __builtin_amdgcn_mfma_f32_16x16x32_bf16(
                        af[m], bfr[n], acc[m][n], 0, 0, 0);
        }
        cur ^= 1;
    }
    #undef STAGE_FIN

    #pragma unroll
    for (int m = 0; m < 4; ++m)
        #pragma unroll
        for (int r4 = 0; r4 < 4; ++r4) {
            int j = j0 + wm * 64 + m * 16 + ((lane >> 4) << 2) + r4;
            size_t rowbase = ((size_t)b * DIMC + j) * HW + n0 + wn * 64 + (lane & 15);
            #pragma unroll
            for (int n = 0; n < 4; ++n)
                out[rowbase + n * 16] = acc[m][n][r4];
        }
}

// ---------------------------------------------------------------------------
// Workspace (bytes):
//   xT    @ 0           67,108,864
//   xmb   @ 67108864    67,108,864
//   Wb    @ 134217728    1,048,576
//   WvT   @ 135266304      524,288
//   Wpb   @ 135790592      524,288
//   G     @ 136314880    4,194,304
//   TU    @ 140509184    8,388,608
//   attnT @ 148897792      524,288
//   Wp2b  @ 149422080    4,194,304
//   Wfb   @ 153616384    4,194,304
//   Gpart @ 157810688   10,485,760
// ---------------------------------------------------------------------------
extern "C" void kernel_launch(void* const* d_in, const int* in_sizes, int n_in,
                              void* d_out, int out_size, void* d_ws, size_t ws_size,
                              hipStream_t stream)
{
    const float* x    = (const float*)d_in[0];
    const float* mask = (const float*)d_in[1];
    const float* Wq   = (const float*)d_in[2];
    const float* Wk   = (const float*)d_in[3];
    const float* Wv   = (const float*)d_in[4];
    const float* Wp   = (const float*)d_in[5];
    float* out = (float*)d_out;
    char* wsb = (char*)d_ws;

    unsigned short* xT   = (unsigned short*)(wsb + 0);
    unsigned short* xmb  = (unsigned short*)(wsb + 67108864);
    unsigned short* Wb   = (unsigned short*)(wsb + 134217728);
    unsigned short* WvT  = (unsigned short*)(wsb + 135266304);
    unsigned short* Wpb  = (unsigned short*)(wsb + 135790592);
    unsigned short* G    = (unsigned short*)(wsb + 136314880);
    unsigned short* TU   = (unsigned short*)(wsb + 140509184);
    unsigned short* attnT= (unsigned short*)(wsb + 148897792);
    unsigned short* Wp2b = (unsigned short*)(wsb + 149422080);
    unsigned short* Wfb  = (unsigned short*)(wsb + 153616384);
    unsigned short* Gpart= (unsigned short*)(wsb + 157810688);

    prep_wx        <<<4928,            256, 0, stream>>>(Wq, Wk, Wv, Wp, x, mask,
                                                         Wb, WvT, Wpb, xT, xmb);
    gram_mfma      <<<320,             256, 0, stream>>>(xmb, Gpart);
    gram_reduce_sym<<<dim3(10, 8),     256, 0, stream>>>(Gpart, G);
    gemm_nn_128    <<<dim3(4, 8, 8),   256, 0, stream>>>(Wb, (size_t)0, G, (size_t)(DIMC*DIMC), TU, (size_t)(1024*DIMC));
    s_softmax      <<<64,              256, 0, stream>>>(TU, Wb, attnT);
    wp2_mfma       <<<dim3(4, 8, 8),   256, 0, stream>>>(Wpb, attnT, Wp2b);
    gemm_nn_128    <<<dim3(4, 4, 8),   256, 0, stream>>>(Wp2b, (size_t)(DIMC*DIMC), WvT, (size_t)0, Wfb, (size_t)(DIMC*DIMC));
    final_mfma     <<<1024,            256, 0, stream>>>(Wfb, xT, out);
}